// Round 6
// baseline (1428.174 us; speedup 1.0000x reference)
//
#include <hip/hip_runtime.h>

typedef _Float16 f16;

#define HW 65536

// own erf (A&S 7.1.26, |err| <= 1.5e-7); __expf is HW v_exp_f32
static __device__ __forceinline__ float my_erf(float v) {
  float x = fabsf(v);
  float t = 1.f / (1.f + 0.3275911f * x);
  float y = t * (0.254829592f + t * (-0.284496736f + t * (1.421413741f
          + t * (-1.453152027f + t * 1.061405429f))));
  float r = 1.f - y * __expf(-x * x);
  return v < 0.f ? -r : r;
}
static __device__ __forceinline__ float my_gelu(float s) {
  return 0.5f * s * (1.f + my_erf(s * 0.70710678118654752f));
}

// keep the harness-template kernel symbol (unused, zero-cost)
__global__ void TRA_Attention_15281493639325_kernel() {}

// diagnostic: fill out with a constant so absmax reveals which precondition failed
__global__ void k_signal(float* out, long long n, float val) {
  long long i = (long long)blockIdx.x * blockDim.x + threadIdx.x;
  long long stride = (long long)gridDim.x * blockDim.x;
  for (; i < n; i += stride) out[i] = val;
}

// ---------------------------------------------------------------------------
// K1 (plain VALU): fused 1x1 conv, 256 out ch.
// A layout: [b][256 ch][HW] f16; ch 0-63 gate, 64-127 q, 128-191 k, 192-255 v.
// grid = nb*256, 256 threads.
// ---------------------------------------------------------------------------
__global__ __launch_bounds__(256) void k1_plain(
    const float* __restrict__ x, const float* __restrict__ w_gate,
    const float* __restrict__ w_qkv, f16* __restrict__ A, float* __restrict__ MARK)
{
  const int tid = threadIdx.x, blk = blockIdx.x;
  const int y = blk & 255, b = blk >> 8;
  const long long pos = (long long)y * 256 + tid;

  float xv[64];
  #pragma unroll
  for (int k = 0; k < 64; ++k)
    xv[k] = x[((long long)b*64 + k)*HW + pos];

  for (int co = 0; co < 256; ++co) {
    const float* wr = (co < 64) ? (w_gate + co*64) : (w_qkv + (co-64)*64);
    float acc = 0.f;
    #pragma unroll
    for (int k = 0; k < 64; ++k) acc += wr[k] * xv[k];
    A[((long long)b*256 + co)*HW + pos] = (f16)acc;
  }
  if (tid == 0) MARK[0] = 1.0f;
}

// ---------------------------------------------------------------------------
// K2a: depthwise 3x3 for gate (+ GELU) and v channels. grid = nb*1024
// ---------------------------------------------------------------------------
__global__ __launch_bounds__(256) void k2a_dw(
    const f16* __restrict__ A, const float* __restrict__ w_gate_dw,
    const float* __restrict__ w_qkv_dw, f16* __restrict__ Vv, f16* __restrict__ GG,
    float* __restrict__ MARK)
{
  __shared__ float ring[3][264];
  const int tid = threadIdx.x, blk = blockIdx.x;
  const int band = blk & 7, ch2 = (blk >> 3) & 127, b = blk >> 10;
  const bool isv = ch2 >= 64;
  const int c = isv ? ch2 - 64 : ch2;
  const f16* src = A + ((long long)b*256 + (isv ? 192 + c : c)) * HW;
  const float* wsrc = isv ? (w_qkv_dw + (128 + c)*9) : (w_gate_dw + c*9);
  f16* dst = (isv ? Vv : GG) + ((long long)b*64 + c) * HW;

  float wd[9];
  #pragma unroll
  for (int j = 0; j < 9; ++j) wd[j] = wsrc[j];

  const int y0 = band * 32;
  auto stage = [&](int yy) {
    int slot = (yy + 3) % 3;
    for (int idx = tid; idx < 258; idx += 256) {
      int xx = idx - 1;
      float v = 0.f;
      if (yy >= 0 && yy < 256 && xx >= 0 && xx < 256)
        v = (float)src[yy*256 + xx];
      ring[slot][idx] = v;
    }
  };
  stage(y0 - 1); stage(y0);
  for (int y = y0; y < y0 + 32; ++y) {
    __syncthreads();
    stage(y + 1);
    __syncthreads();
    int xx = tid;
    float s = 0.f;
    #pragma unroll
    for (int dy = -1; dy <= 1; ++dy) {
      const float* r = ring[(y + dy + 3) % 3];
      #pragma unroll
      for (int dx = 0; dx < 3; ++dx)
        s += wd[(dy+1)*3 + dx] * r[xx + dx];
    }
    if (isv) dst[y*256 + xx] = (f16)s;
    else     dst[y*256 + xx] = (f16)my_gelu(s);
  }
  if (tid == 0) MARK[1] = 1.0f;
}

// ---------------------------------------------------------------------------
// K2b: depthwise 3x3 for q,k of one head + fused gram partials (qq,kk,qk).
// GRP layout: [b][h][band][80]. grid = nb*64
// ---------------------------------------------------------------------------
__global__ __launch_bounds__(256) void k2b_qk(
    const f16* __restrict__ A, const float* __restrict__ w_qkv_dw,
    float* __restrict__ GRP, float* __restrict__ MARK)
{
  __shared__ f16 ring[16][3][264];
  __shared__ float wq[16][9];
  __shared__ float red[4][80];
  const int tid = threadIdx.x, blk = blockIdx.x;
  const int band = blk & 7, h = (blk >> 3) & 7, b = blk >> 6;

  for (int idx = tid; idx < 144; idx += 256) {
    int ch = idx / 9, j = idx % 9;
    int row = (ch < 8) ? (h*8 + ch) : (64 + h*8 + (ch - 8));
    wq[ch][j] = w_qkv_dw[row*9 + j];
  }

  const f16* qbase = A + ((long long)b*256 + 64  + h*8) * HW;
  const f16* kbase = A + ((long long)b*256 + 128 + h*8) * HW;

  const int y0 = band * 32;
  auto stage = [&](int yy) {
    int slot = (yy + 3) % 3;
    for (int idx = tid; idx < 16*258; idx += 256) {
      int ch = idx / 258, i = idx % 258, xx = i - 1;
      f16 v = (f16)0.f;
      if (yy >= 0 && yy < 256 && xx >= 0 && xx < 256)
        v = (ch < 8 ? qbase + ch*HW : kbase + (ch-8)*HW)[yy*256 + xx];
      ring[ch][slot][i] = v;
    }
  };

  float aqq[8] = {0}, akk[8] = {0}, aqk[64] = {0};
  stage(y0 - 1); stage(y0);
  for (int y = y0; y < y0 + 32; ++y) {
    __syncthreads();
    stage(y + 1);
    __syncthreads();
    const int xx = tid;
    float qv[8], kv[8];
    #pragma unroll
    for (int ch = 0; ch < 16; ++ch) {
      float s = 0.f;
      #pragma unroll
      for (int dy = -1; dy <= 1; ++dy) {
        const f16* r = ring[ch][(y + dy + 3) % 3];
        #pragma unroll
        for (int dx = 0; dx < 3; ++dx)
          s += wq[ch][(dy+1)*3 + dx] * (float)r[xx + dx];
      }
      if (ch < 8) qv[ch] = s; else kv[ch - 8] = s;
    }
    #pragma unroll
    for (int cc = 0; cc < 8; ++cc) {
      aqq[cc] += qv[cc]*qv[cc];
      akk[cc] += kv[cc]*kv[cc];
      #pragma unroll
      for (int dd = 0; dd < 8; ++dd)
        aqk[cc*8 + dd] += qv[cc]*kv[dd];
    }
  }
  __syncthreads();
  const int wave = tid >> 6, lane = tid & 63;
  #pragma unroll
  for (int i = 0; i < 80; ++i) {
    float v = (i < 8) ? aqq[i] : (i < 16 ? akk[i-8] : aqk[i-16]);
    #pragma unroll
    for (int off = 32; off; off >>= 1) v += __shfl_xor(v, off);
    if (lane == 0) red[wave][i] = v;
  }
  __syncthreads();
  for (int i = tid; i < 80; i += 256) {
    float v = red[0][i] + red[1][i] + red[2][i] + red[3][i];
    GRP[(((b*8 + h)*8 + band) * 80) + i] = v;
  }
  if (tid == 0) MARK[2] = 1.0f;
}

// ---------------------------------------------------------------------------
// K2c: reduce band partials, normalize, temperature, softmax. grid = nb*8
// ---------------------------------------------------------------------------
__global__ __launch_bounds__(64) void k2c_attn(
    const float* __restrict__ GRP, const float* __restrict__ temp,
    float* __restrict__ ATT, float* __restrict__ MARK)
{
  __shared__ float s[80];
  const int tid = threadIdx.x;
  const int h = blockIdx.x & 7, b = blockIdx.x >> 3;
  for (int i = tid; i < 80; i += 64) {
    float v = 0.f;
    for (int band = 0; band < 8; ++band)
      v += GRP[(((b*8 + h)*8 + band) * 80) + i];
    s[i] = v;
  }
  __syncthreads();
  const int c = tid >> 3, d = tid & 7;
  float nq = fmaxf(sqrtf(s[c]), 1e-12f);
  float nk = fmaxf(sqrtf(s[8 + d]), 1e-12f);
  float logit = s[16 + c*8 + d] / (nq * nk) * temp[h];
  float m = logit;
  #pragma unroll
  for (int off = 4; off; off >>= 1) m = fmaxf(m, __shfl_xor(m, off));
  float e = __expf(logit - m);
  float sum = e;
  #pragma unroll
  for (int off = 4; off; off >>= 1) sum += __shfl_xor(sum, off);
  ATT[((b*8 + h)*8 + c)*8 + d] = e / sum;
  if (tid == 0) MARK[3] = 1.0f;
}

// ---------------------------------------------------------------------------
// K3: out = conv1x1( gelu(gate) * (attn @ v), w_proj ). grid = nb*256
// OUTPUT IS FLOAT32.
// ---------------------------------------------------------------------------
__global__ __launch_bounds__(256) void k3_out(
    const f16* __restrict__ Vv, const f16* __restrict__ GG,
    const float* __restrict__ ATT, const float* __restrict__ w_proj,
    float* __restrict__ out, float* __restrict__ MARK)
{
  __shared__ float attn_s[512];
  __shared__ float wp[4096];
  const int tid = threadIdx.x;
  const int y = blockIdx.x & 255, b = blockIdx.x >> 8;
  for (int i = tid; i < 512; i += 256) attn_s[i] = ATT[b*512 + i];
  for (int i = tid; i < 4096; i += 256) wp[i] = w_proj[i];
  __syncthreads();

  const int xx = tid;
  const long long pos = (long long)y*256 + xx;
  float g[64];
  #pragma unroll
  for (int hd = 0; hd < 8; ++hd) {
    float vv[8];
    #pragma unroll
    for (int d = 0; d < 8; ++d)
      vv[d] = (float)Vv[((long long)b*64 + hd*8 + d)*HW + pos];
    #pragma unroll
    for (int c = 0; c < 8; ++c) {
      float av = 0.f;
      #pragma unroll
      for (int d = 0; d < 8; ++d)
        av += attn_s[hd*64 + c*8 + d] * vv[d];
      float gg = (float)GG[((long long)b*64 + hd*8 + c)*HW + pos];
      g[hd*8 + c] = gg * av;
    }
  }
  for (int co = 0; co < 64; ++co) {
    float acc = 0.f;
    const float4* wr = (const float4*)(wp + co*64);
    #pragma unroll
    for (int q4 = 0; q4 < 16; ++q4) {
      float4 wv = wr[q4];
      acc += wv.x * g[q4*4 + 0] + wv.y * g[q4*4 + 1]
           + wv.z * g[q4*4 + 2] + wv.w * g[q4*4 + 3];
    }
    out[((long long)b*64 + co)*HW + pos] = acc;
  }
  if (tid == 0) MARK[4] = 1.0f;
}

// ---------------------------------------------------------------------------
// K_diag: flags: 1=k1 ran, 2=k2a, 4=k2b, 8=k2c, 16=k3, 32=out nonzero.
// Healthy = 63 -> writes nothing. Else flood out with (64+code).
// ---------------------------------------------------------------------------
__global__ __launch_bounds__(256) void k_diag(
    const float* __restrict__ MARK, float* __restrict__ out, long long nOut)
{
  __shared__ int alive;
  __shared__ int code_s;
  const int tid = threadIdx.x;
  if (tid == 0) alive = 0;
  __syncthreads();
  int ao = 0;
  for (int i = 0; i < 16; ++i) {
    long long j = ((long long)(tid*16 + i) * 52429LL) % nOut;
    if (out[j] != 0.f) ao = 1;
  }
  if (ao) alive = 1;
  __syncthreads();
  if (tid == 0) {
    int code = 0;
    if (MARK[0] == 1.0f) code |= 1;
    if (MARK[1] == 1.0f) code |= 2;
    if (MARK[2] == 1.0f) code |= 4;
    if (MARK[3] == 1.0f) code |= 8;
    if (MARK[4] == 1.0f) code |= 16;
    if (alive)           code |= 32;
    code_s = code;
  }
  __syncthreads();
  int code = code_s;
  if (code != 63) {
    float u = (float)(64 + code);
    for (long long i = tid; i < nOut; i += 256) out[i] = u;
  }
}

// ---------------------------------------------------------------------------
extern "C" void kernel_launch(void* const* d_in, const int* in_sizes, int n_in,
                              void* d_out, int out_size, void* d_ws, size_t ws_size,
                              hipStream_t stream)
{
  float* out = (float*)d_out;

  int mp[7] = {-1,-1,-1,-1,-1,-1,-1};
  bool ok = (n_in == 7);
  if (ok) {
    int n4 = 0;
    for (int i = 0; i < 7; ++i) {
      long s = in_sizes[i];
      if      (s == 33554432) mp[0] = i;            // x
      else if (s == 576)      mp[2] = i;            // w_gate_dw
      else if (s == 12288)    mp[3] = i;            // w_qkv
      else if (s == 1728)     mp[4] = i;            // w_qkv_dw
      else if (s == 8)        mp[6] = i;            // temperature
      else if (s == 4096)     { if (n4 == 0) mp[1] = i; else mp[5] = i; ++n4; }
    }
    ok = ok && (n4 == 2);
    for (int i = 0; i < 7; ++i) ok = ok && (mp[i] >= 0);
  }
  if (!ok) { k_signal<<<2048,256,0,stream>>>(out, (long long)out_size, 2000.0f); return; }
  if (out_size != 33554432) { k_signal<<<2048,256,0,stream>>>(out, (long long)out_size, 3000.0f); return; }

  const float* x    = (const float*)d_in[mp[0]];
  const float* wg   = (const float*)d_in[mp[1]];
  const float* wgd  = (const float*)d_in[mp[2]];
  const float* wqkv = (const float*)d_in[mp[3]];
  const float* wqd  = (const float*)d_in[mp[4]];
  const float* wpj  = (const float*)d_in[mp[5]];
  const float* tp   = (const float*)d_in[mp[6]];

  unsigned char* ws = (unsigned char*)d_ws;
  const size_t FULL = 402833472UL;
  const size_t PERB = 50354240UL;

  if (ws != nullptr && ws_size >= FULL) {
    f16*   A    = (f16*)ws;                          // 268,435,456
    f16*   Vv   = (f16*)(ws + 268435456UL);          //  67,108,864
    f16*   GG   = (f16*)(ws + 335544320UL);          //  67,108,864
    float* GRP  = (float*)(ws + 402653184UL);        //     163,840
    float* ATT  = (float*)(ws + 402817024UL);        //      16,384
    float* MARK = (float*)(ws + 402833408UL);        //          64
    k1_plain<<<2048, 256, 0, stream>>>(x, wg, wqkv, A, MARK);
    k2a_dw  <<<8192, 256, 0, stream>>>(A, wgd, wqd, Vv, GG, MARK);
    k2b_qk  <<<512,  256, 0, stream>>>(A, wqd, GRP, MARK);
    k2c_attn<<<64,   64,  0, stream>>>(GRP, tp, ATT, MARK);
    k3_out  <<<2048, 256, 0, stream>>>(Vv, GG, ATT, wpj, out, MARK);
    k_diag  <<<1,    256, 0, stream>>>(MARK, out, 33554432LL);
  } else if (ws != nullptr && ws_size >= PERB) {
    f16*   A    = (f16*)ws;                          // 33,554,432
    f16*   Vv   = (f16*)(ws + 33554432UL);           //  8,388,608
    f16*   GG   = (f16*)(ws + 41943040UL);           //  8,388,608
    float* GRP  = (float*)(ws + 50331648UL);         //     20,480
    float* ATT  = (float*)(ws + 50352128UL);         //      2,048
    float* MARK = (float*)(ws + 50354176UL);         //          64
    for (int b = 0; b < 8; ++b) {
      const float* xb = x + (long long)b*64*HW;
      float* ob = out + (long long)b*64*HW;
      k1_plain<<<256,  256, 0, stream>>>(xb, wg, wqkv, A, MARK);
      k2a_dw  <<<1024, 256, 0, stream>>>(A, wgd, wqd, Vv, GG, MARK);
      k2b_qk  <<<64,   256, 0, stream>>>(A, wqd, GRP, MARK);
      k2c_attn<<<8,    64,  0, stream>>>(GRP, tp, ATT, MARK);
      k3_out  <<<256,  256, 0, stream>>>(Vv, GG, ATT, wpj, ob, MARK);
    }
    k_diag  <<<1, 256, 0, stream>>>(MARK, out, 33554432LL);
  } else {
    k_signal<<<2048,256,0,stream>>>(out, (long long)out_size, 1000.0f);
  }
}

// Round 7
// 1077.829 us; speedup vs baseline: 1.3250x; 1.3250x over previous
//
#include <hip/hip_runtime.h>

typedef _Float16 f16;
using f16x8 = __attribute__((ext_vector_type(8))) _Float16;
using f32x4 = __attribute__((ext_vector_type(4))) float;

#define HW 65536

// own erf (A&S 7.1.26, |err| <= 1.5e-7); __expf is HW v_exp_f32
static __device__ __forceinline__ float my_erf(float v) {
  float x = fabsf(v);
  float t = 1.f / (1.f + 0.3275911f * x);
  float y = t * (0.254829592f + t * (-0.284496736f + t * (1.421413741f
          + t * (-1.453152027f + t * 1.061405429f))));
  float r = 1.f - y * __expf(-x * x);
  return v < 0.f ? -r : r;
}
static __device__ __forceinline__ float my_gelu(float s) {
  return 0.5f * s * (1.f + my_erf(s * 0.70710678118654752f));
}

__global__ void TRA_Attention_15281493639325_kernel() {}

__global__ void k_signal(float* out, long long n, float val) {
  long long i = (long long)blockIdx.x * blockDim.x + threadIdx.x;
  long long stride = (long long)gridDim.x * blockDim.x;
  for (; i < n; i += stride) out[i] = val;
}

// ---------------------------------------------------------------------------
// K1 (MFMA f16): fused 1x1 conv, 256 out ch. Tile M=256 x N=64 pos, K=64.
// 256 thr (4 waves): wave m0=(w>>1)*128, n0=(w&1)*32; 8x2 16x16 frags/wave.
// A layout: [b][256 ch][HW] f16; ch 0-63 gate, 64-127 q, 128-191 k, 192-255 v.
// grid = nb*1024. LDS 40KB (W 32KB + xT 8KB), XOR-swizzled 16B chunks.
// ---------------------------------------------------------------------------
__global__ __launch_bounds__(256) void k1_mfma(
    const float* __restrict__ x, const float* __restrict__ w_gate,
    const float* __restrict__ w_qkv, f16* __restrict__ A)
{
  __shared__ __align__(16) unsigned char lds[256*128 + 64*128];
  unsigned char* wl = lds;            // W: 256 rows x 128B (64 f16)
  unsigned char* xs = lds + 256*128;  // xT: 64 pos-rows x 128B

  const int tid = threadIdx.x, blk = blockIdx.x;
  const int b = blk >> 10;
  const long long p0 = (long long)(blk & 1023) * 64;

  // stage weights: 256 rows x 16 float4 chunks, f32 -> f16, XOR-swizzled
  for (int cid = tid; cid < 4096; cid += 256) {
    int m = cid >> 4, kc = cid & 15;
    const float* src = (m < 64) ? (w_gate + m*64 + kc*4)
                                : (w_qkv + (m-64)*64 + kc*4);
    float4 f = *(const float4*)src;
    int hm = ((m & 7) ^ ((m >> 3) & 7)) << 4;
    f16* dst = (f16*)(wl + m*128 + ((kc*8) ^ hm));
    dst[0]=(f16)f.x; dst[1]=(f16)f.y; dst[2]=(f16)f.z; dst[3]=(f16)f.w;
  }
  // stage x tile transposed: xs[p][k], from x[b][k][p0..p0+63]
  for (int cid = tid; cid < 1024; cid += 256) {
    int k = cid >> 4, c = cid & 15;
    float4 f = *(const float4*)(x + ((long long)b*64 + k)*HW + p0 + c*4);
    const float* e = (const float*)&f;
    #pragma unroll
    for (int i = 0; i < 4; ++i) {
      int p = c*4 + i;
      int hp = ((p & 7) ^ ((p >> 3) & 7)) << 4;
      *(f16*)(xs + p*128 + ((2*k) ^ hp)) = (f16)e[i];
    }
  }
  __syncthreads();

  const int wave = tid >> 6, lane = tid & 63;
  const int m0 = (wave >> 1) * 128, n0 = (wave & 1) * 32;
  const int lr = lane & 15, lg = lane >> 4;

  f32x4 acc[8][2];
  #pragma unroll
  for (int i = 0; i < 8; ++i)
    #pragma unroll
    for (int j = 0; j < 2; ++j) acc[i][j] = (f32x4){0.f,0.f,0.f,0.f};

  #pragma unroll
  for (int ks = 0; ks < 2; ++ks) {
    f16x8 af[8], bfr[2];
    #pragma unroll
    for (int mi = 0; mi < 8; ++mi) {
      int m = m0 + mi*16 + lr;
      int hm = ((m & 7) ^ ((m >> 3) & 7)) << 4;
      af[mi] = *(const f16x8*)(wl + m*128 + ((ks*64 + lg*16) ^ hm));
    }
    #pragma unroll
    for (int ni = 0; ni < 2; ++ni) {
      int p = n0 + ni*16 + lr;
      int hp = ((p & 7) ^ ((p >> 3) & 7)) << 4;
      bfr[ni] = *(const f16x8*)(xs + p*128 + ((ks*64 + lg*16) ^ hp));
    }
    #pragma unroll
    for (int mi = 0; mi < 8; ++mi)
      #pragma unroll
      for (int ni = 0; ni < 2; ++ni)
        acc[mi][ni] = __builtin_amdgcn_mfma_f32_16x16x32_f16(
            af[mi], bfr[ni], acc[mi][ni], 0, 0, 0);
  }

  // D: col(=pos) = lane&15, row(=ch) = (lane>>4)*4 + r
  #pragma unroll
  for (int mi = 0; mi < 8; ++mi)
    #pragma unroll
    for (int ni = 0; ni < 2; ++ni)
      #pragma unroll
      for (int r = 0; r < 4; ++r) {
        int m = m0 + mi*16 + lg*4 + r;
        long long p = p0 + n0 + ni*16 + lr;
        A[((long long)b*256 + m)*HW + p] = (f16)acc[mi][ni][r];
      }
}

// ---------------------------------------------------------------------------
// K2a: depthwise 3x3 for gate (+ GELU) and v channels.
// Whole 34-row window staged in LDS once (1 barrier). grid = nb*1024.
// ---------------------------------------------------------------------------
__global__ __launch_bounds__(256) void k2a_dw(
    const f16* __restrict__ A, const float* __restrict__ w_gate_dw,
    const float* __restrict__ w_qkv_dw, f16* __restrict__ Vv, f16* __restrict__ GG)
{
  __shared__ f16 tile[34][258];
  const int tid = threadIdx.x, blk = blockIdx.x;
  const int band = blk & 7, ch2 = (blk >> 3) & 127, b = blk >> 10;
  const bool isv = ch2 >= 64;
  const int c = isv ? ch2 - 64 : ch2;
  const f16* src = A + ((long long)b*256 + (isv ? 192 + c : c)) * HW;
  const float* wsrc = isv ? (w_qkv_dw + (128 + c)*9) : (w_gate_dw + c*9);
  f16* dst = (isv ? Vv : GG) + ((long long)b*64 + c) * HW;

  float wd[9];
  #pragma unroll
  for (int j = 0; j < 9; ++j) wd[j] = wsrc[j];

  const int y0 = band * 32;
  #pragma unroll 2
  for (int r = 0; r < 34; ++r) {
    int y = y0 - 1 + r;
    f16 v = (f16)0.f;
    if (y >= 0 && y < 256) v = src[y*256 + tid];
    tile[r][1 + tid] = v;
    if (tid < 2) tile[r][tid ? 257 : 0] = (f16)0.f;
  }
  __syncthreads();

  for (int yy = 0; yy < 32; ++yy) {
    float s = 0.f;
    #pragma unroll
    for (int dy = 0; dy < 3; ++dy)
      #pragma unroll
      for (int dx = 0; dx < 3; ++dx)
        s += wd[dy*3 + dx] * (float)tile[yy + dy][tid + dx];
    int y = y0 + yy;
    if (isv) dst[y*256 + tid] = (f16)s;
    else     dst[y*256 + tid] = (f16)my_gelu(s);
  }
}

// ---------------------------------------------------------------------------
// K2b: depthwise 3x3 for q,k of one head + fused gram partials (qq,kk,qk).
// GRP layout: [b][h][band][80]. grid = nb*64
// ---------------------------------------------------------------------------
__global__ __launch_bounds__(256) void k2b_qk(
    const f16* __restrict__ A, const float* __restrict__ w_qkv_dw,
    float* __restrict__ GRP)
{
  __shared__ f16 ring[16][3][264];
  __shared__ float wq[16][9];
  __shared__ float red[4][80];
  const int tid = threadIdx.x, blk = blockIdx.x;
  const int band = blk & 7, h = (blk >> 3) & 7, b = blk >> 6;

  for (int idx = tid; idx < 144; idx += 256) {
    int ch = idx / 9, j = idx % 9;
    int row = (ch < 8) ? (h*8 + ch) : (64 + h*8 + (ch - 8));
    wq[ch][j] = w_qkv_dw[row*9 + j];
  }

  const f16* qbase = A + ((long long)b*256 + 64  + h*8) * HW;
  const f16* kbase = A + ((long long)b*256 + 128 + h*8) * HW;

  const int y0 = band * 32;
  auto stage = [&](int yy) {
    int slot = (yy + 3) % 3;
    for (int idx = tid; idx < 16*258; idx += 256) {
      int ch = idx / 258, i = idx % 258, xx = i - 1;
      f16 v = (f16)0.f;
      if (yy >= 0 && yy < 256 && xx >= 0 && xx < 256)
        v = (ch < 8 ? qbase + ch*HW : kbase + (ch-8)*HW)[yy*256 + xx];
      ring[ch][slot][i] = v;
    }
  };

  float aqq[8] = {0}, akk[8] = {0}, aqk[64] = {0};
  stage(y0 - 1); stage(y0);
  for (int y = y0; y < y0 + 32; ++y) {
    __syncthreads();
    stage(y + 1);
    __syncthreads();
    const int xx = tid;
    float qv[8], kv[8];
    #pragma unroll
    for (int ch = 0; ch < 16; ++ch) {
      float s = 0.f;
      #pragma unroll
      for (int dy = -1; dy <= 1; ++dy) {
        const f16* r = ring[ch][(y + dy + 3) % 3];
        #pragma unroll
        for (int dx = 0; dx < 3; ++dx)
          s += wq[ch][(dy+1)*3 + dx] * (float)r[xx + dx];
      }
      if (ch < 8) qv[ch] = s; else kv[ch - 8] = s;
    }
    #pragma unroll
    for (int cc = 0; cc < 8; ++cc) {
      aqq[cc] += qv[cc]*qv[cc];
      akk[cc] += kv[cc]*kv[cc];
      #pragma unroll
      for (int dd = 0; dd < 8; ++dd)
        aqk[cc*8 + dd] += qv[cc]*kv[dd];
    }
  }
  __syncthreads();
  const int wave = tid >> 6, lane = tid & 63;
  #pragma unroll
  for (int i = 0; i < 80; ++i) {
    float v = (i < 8) ? aqq[i] : (i < 16 ? akk[i-8] : aqk[i-16]);
    #pragma unroll
    for (int off = 32; off; off >>= 1) v += __shfl_xor(v, off);
    if (lane == 0) red[wave][i] = v;
  }
  __syncthreads();
  for (int i = tid; i < 80; i += 256) {
    float v = red[0][i] + red[1][i] + red[2][i] + red[3][i];
    GRP[(((b*8 + h)*8 + band) * 80) + i] = v;
  }
}

// ---------------------------------------------------------------------------
// K2c: reduce band partials, normalize, temperature, softmax. grid = nb*8
// ---------------------------------------------------------------------------
__global__ __launch_bounds__(64) void k2c_attn(
    const float* __restrict__ GRP, const float* __restrict__ temp,
    float* __restrict__ ATT)
{
  __shared__ float s[80];
  const int tid = threadIdx.x;
  const int h = blockIdx.x & 7, b = blockIdx.x >> 3;
  for (int i = tid; i < 80; i += 64) {
    float v = 0.f;
    for (int band = 0; band < 8; ++band)
      v += GRP[(((b*8 + h)*8 + band) * 80) + i];
    s[i] = v;
  }
  __syncthreads();
  const int c = tid >> 3, d = tid & 7;
  float nq = fmaxf(sqrtf(s[c]), 1e-12f);
  float nk = fmaxf(sqrtf(s[8 + d]), 1e-12f);
  float logit = s[16 + c*8 + d] / (nq * nk) * temp[h];
  float m = logit;
  #pragma unroll
  for (int off = 4; off; off >>= 1) m = fmaxf(m, __shfl_xor(m, off));
  float e = __expf(logit - m);
  float sum = e;
  #pragma unroll
  for (int off = 4; off; off >>= 1) sum += __shfl_xor(sum, off);
  ATT[((b*8 + h)*8 + c)*8 + d] = e / sum;
}

// ---------------------------------------------------------------------------
// K3: out = conv1x1( gelu(gate) * (attn @ v), w_proj ). grid = nb*256. f32 out.
// ---------------------------------------------------------------------------
__global__ __launch_bounds__(256) void k3_out(
    const f16* __restrict__ Vv, const f16* __restrict__ GG,
    const float* __restrict__ ATT, const float* __restrict__ w_proj,
    float* __restrict__ out)
{
  __shared__ float attn_s[512];
  __shared__ float wp[4096];
  const int tid = threadIdx.x;
  const int y = blockIdx.x & 255, b = blockIdx.x >> 8;
  for (int i = tid; i < 512; i += 256) attn_s[i] = ATT[b*512 + i];
  for (int i = tid; i < 4096; i += 256) wp[i] = w_proj[i];
  __syncthreads();

  const int xx = tid;
  const long long pos = (long long)y*256 + xx;
  float g[64];
  #pragma unroll
  for (int hd = 0; hd < 8; ++hd) {
    float vv[8];
    #pragma unroll
    for (int d = 0; d < 8; ++d)
      vv[d] = (float)Vv[((long long)b*64 + hd*8 + d)*HW + pos];
    #pragma unroll
    for (int c = 0; c < 8; ++c) {
      float av = 0.f;
      #pragma unroll
      for (int d = 0; d < 8; ++d)
        av += attn_s[hd*64 + c*8 + d] * vv[d];
      float gg = (float)GG[((long long)b*64 + hd*8 + c)*HW + pos];
      g[hd*8 + c] = gg * av;
    }
  }
  for (int co = 0; co < 64; ++co) {
    float acc = 0.f;
    const float4* wr = (const float4*)(wp + co*64);
    #pragma unroll
    for (int q4 = 0; q4 < 16; ++q4) {
      float4 wv = wr[q4];
      acc += wv.x * g[q4*4 + 0] + wv.y * g[q4*4 + 1]
           + wv.z * g[q4*4 + 2] + wv.w * g[q4*4 + 3];
    }
    out[((long long)b*64 + co)*HW + pos] = acc;
  }
}

// ---------------------------------------------------------------------------
extern "C" void kernel_launch(void* const* d_in, const int* in_sizes, int n_in,
                              void* d_out, int out_size, void* d_ws, size_t ws_size,
                              hipStream_t stream)
{
  float* out = (float*)d_out;

  int mp[7] = {-1,-1,-1,-1,-1,-1,-1};
  bool ok = (n_in == 7);
  if (ok) {
    int n4 = 0;
    for (int i = 0; i < 7; ++i) {
      long s = in_sizes[i];
      if      (s == 33554432) mp[0] = i;            // x
      else if (s == 576)      mp[2] = i;            // w_gate_dw
      else if (s == 12288)    mp[3] = i;            // w_qkv
      else if (s == 1728)     mp[4] = i;            // w_qkv_dw
      else if (s == 8)        mp[6] = i;            // temperature
      else if (s == 4096)     { if (n4 == 0) mp[1] = i; else mp[5] = i; ++n4; }
    }
    ok = ok && (n4 == 2);
    for (int i = 0; i < 7; ++i) ok = ok && (mp[i] >= 0);
  }
  if (!ok) { k_signal<<<2048,256,0,stream>>>(out, (long long)out_size, 2000.0f); return; }
  if (out_size != 33554432) { k_signal<<<2048,256,0,stream>>>(out, (long long)out_size, 3000.0f); return; }

  const float* x    = (const float*)d_in[mp[0]];
  const float* wg   = (const float*)d_in[mp[1]];
  const float* wgd  = (const float*)d_in[mp[2]];
  const float* wqkv = (const float*)d_in[mp[3]];
  const float* wqd  = (const float*)d_in[mp[4]];
  const float* wpj  = (const float*)d_in[mp[5]];
  const float* tp   = (const float*)d_in[mp[6]];

  unsigned char* ws = (unsigned char*)d_ws;
  const size_t FULL = 402833408UL;
  const size_t PERB = 50354176UL;

  if (ws != nullptr && ws_size >= FULL) {
    f16*   A    = (f16*)ws;                          // 268,435,456
    f16*   Vv   = (f16*)(ws + 268435456UL);          //  67,108,864
    f16*   GG   = (f16*)(ws + 335544320UL);          //  67,108,864
    float* GRP  = (float*)(ws + 402653184UL);        //     163,840
    float* ATT  = (float*)(ws + 402817024UL);        //      16,384
    k1_mfma <<<8192, 256, 0, stream>>>(x, wg, wqkv, A);
    k2a_dw  <<<8192, 256, 0, stream>>>(A, wgd, wqd, Vv, GG);
    k2b_qk  <<<512,  256, 0, stream>>>(A, wqd, GRP);
    k2c_attn<<<64,   64,  0, stream>>>(GRP, tp, ATT);
    k3_out  <<<2048, 256, 0, stream>>>(Vv, GG, ATT, wpj, out);
  } else if (ws != nullptr && ws_size >= PERB) {
    f16*   A    = (f16*)ws;                          // 33,554,432
    f16*   Vv   = (f16*)(ws + 33554432UL);           //  8,388,608
    f16*   GG   = (f16*)(ws + 41943040UL);           //  8,388,608
    float* GRP  = (float*)(ws + 50331648UL);         //     20,480
    float* ATT  = (float*)(ws + 50352128UL);         //      2,048
    for (int b = 0; b < 8; ++b) {
      const float* xb = x + (long long)b*64*HW;
      float* ob = out + (long long)b*64*HW;
      k1_mfma <<<1024, 256, 0, stream>>>(xb, wg, wqkv, A);
      k2a_dw  <<<1024, 256, 0, stream>>>(A, wgd, wqd, Vv, GG);
      k2b_qk  <<<64,   256, 0, stream>>>(A, wqd, GRP);
      k2c_attn<<<8,    64,  0, stream>>>(GRP, tp, ATT);
      k3_out  <<<256,  256, 0, stream>>>(Vv, GG, ATT, wpj, ob);
    }
  } else {
    k_signal<<<2048,256,0,stream>>>(out, (long long)out_size, 1000.0f);
  }
}

// Round 8
// 913.270 us; speedup vs baseline: 1.5638x; 1.1802x over previous
//
#include <hip/hip_runtime.h>

typedef _Float16 f16;
using f16x8 = __attribute__((ext_vector_type(8))) _Float16;
using f32x4 = __attribute__((ext_vector_type(4))) float;

#define HW 65536
#define NBAND 32

// own erf (A&S 7.1.26, |err| <= 1.5e-7); __expf is HW v_exp_f32
static __device__ __forceinline__ float my_erf(float v) {
  float x = fabsf(v);
  float t = 1.f / (1.f + 0.3275911f * x);
  float y = t * (0.254829592f + t * (-0.284496736f + t * (1.421413741f
          + t * (-1.453152027f + t * 1.061405429f))));
  float r = 1.f - y * __expf(-x * x);
  return v < 0.f ? -r : r;
}
static __device__ __forceinline__ float my_gelu(float s) {
  return 0.5f * s * (1.f + my_erf(s * 0.70710678118654752f));
}

__global__ void TRA_Attention_15281493639325_kernel() {}

__global__ void k_signal(float* out, long long n, float val) {
  long long i = (long long)blockIdx.x * blockDim.x + threadIdx.x;
  long long stride = (long long)gridDim.x * blockDim.x;
  for (; i < n; i += stride) out[i] = val;
}

// ---------------------------------------------------------------------------
// K1 (MFMA f16): fused 1x1 conv, 256 out ch. Tile M=256 x N=64 pos, K=64.
// grid = nb*1024. LDS 40KB, XOR-swizzled 16B chunks.
// ---------------------------------------------------------------------------
__global__ __launch_bounds__(256) void k1_mfma(
    const float* __restrict__ x, const float* __restrict__ w_gate,
    const float* __restrict__ w_qkv, f16* __restrict__ A)
{
  __shared__ __align__(16) unsigned char lds[256*128 + 64*128];
  unsigned char* wl = lds;
  unsigned char* xs = lds + 256*128;

  const int tid = threadIdx.x, blk = blockIdx.x;
  const int b = blk >> 10;
  const long long p0 = (long long)(blk & 1023) * 64;

  for (int cid = tid; cid < 4096; cid += 256) {
    int m = cid >> 4, kc = cid & 15;
    const float* src = (m < 64) ? (w_gate + m*64 + kc*4)
                                : (w_qkv + (m-64)*64 + kc*4);
    float4 f = *(const float4*)src;
    int hm = ((m & 7) ^ ((m >> 3) & 7)) << 4;
    f16* dst = (f16*)(wl + m*128 + ((kc*8) ^ hm));
    dst[0]=(f16)f.x; dst[1]=(f16)f.y; dst[2]=(f16)f.z; dst[3]=(f16)f.w;
  }
  for (int cid = tid; cid < 1024; cid += 256) {
    int k = cid >> 4, c = cid & 15;
    float4 f = *(const float4*)(x + ((long long)b*64 + k)*HW + p0 + c*4);
    const float* e = (const float*)&f;
    #pragma unroll
    for (int i = 0; i < 4; ++i) {
      int p = c*4 + i;
      int hp = ((p & 7) ^ ((p >> 3) & 7)) << 4;
      *(f16*)(xs + p*128 + ((2*k) ^ hp)) = (f16)e[i];
    }
  }
  __syncthreads();

  const int wave = tid >> 6, lane = tid & 63;
  const int m0 = (wave >> 1) * 128, n0 = (wave & 1) * 32;
  const int lr = lane & 15, lg = lane >> 4;

  f32x4 acc[8][2];
  #pragma unroll
  for (int i = 0; i < 8; ++i)
    #pragma unroll
    for (int j = 0; j < 2; ++j) acc[i][j] = (f32x4){0.f,0.f,0.f,0.f};

  #pragma unroll
  for (int ks = 0; ks < 2; ++ks) {
    f16x8 af[8], bfr[2];
    #pragma unroll
    for (int mi = 0; mi < 8; ++mi) {
      int m = m0 + mi*16 + lr;
      int hm = ((m & 7) ^ ((m >> 3) & 7)) << 4;
      af[mi] = *(const f16x8*)(wl + m*128 + ((ks*64 + lg*16) ^ hm));
    }
    #pragma unroll
    for (int ni = 0; ni < 2; ++ni) {
      int p = n0 + ni*16 + lr;
      int hp = ((p & 7) ^ ((p >> 3) & 7)) << 4;
      bfr[ni] = *(const f16x8*)(xs + p*128 + ((ks*64 + lg*16) ^ hp));
    }
    #pragma unroll
    for (int mi = 0; mi < 8; ++mi)
      #pragma unroll
      for (int ni = 0; ni < 2; ++ni)
        acc[mi][ni] = __builtin_amdgcn_mfma_f32_16x16x32_f16(
            af[mi], bfr[ni], acc[mi][ni], 0, 0, 0);
  }

  #pragma unroll
  for (int mi = 0; mi < 8; ++mi)
    #pragma unroll
    for (int ni = 0; ni < 2; ++ni)
      #pragma unroll
      for (int r = 0; r < 4; ++r) {
        int m = m0 + mi*16 + lg*4 + r;
        long long p = p0 + n0 + ni*16 + lr;
        A[((long long)b*256 + m)*HW + p] = (f16)acc[mi][ni][r];
      }
}

// ---------------------------------------------------------------------------
// K2a: depthwise 3x3 for gate (+ GELU) and v channels. 1 barrier. grid=nb*1024
// ---------------------------------------------------------------------------
__global__ __launch_bounds__(256) void k2a_dw(
    const f16* __restrict__ A, const float* __restrict__ w_gate_dw,
    const float* __restrict__ w_qkv_dw, f16* __restrict__ Vv, f16* __restrict__ GG)
{
  __shared__ f16 tile[34][258];
  const int tid = threadIdx.x, blk = blockIdx.x;
  const int band = blk & 7, ch2 = (blk >> 3) & 127, b = blk >> 10;
  const bool isv = ch2 >= 64;
  const int c = isv ? ch2 - 64 : ch2;
  const f16* src = A + ((long long)b*256 + (isv ? 192 + c : c)) * HW;
  const float* wsrc = isv ? (w_qkv_dw + (128 + c)*9) : (w_gate_dw + c*9);
  f16* dst = (isv ? Vv : GG) + ((long long)b*64 + c) * HW;

  float wd[9];
  #pragma unroll
  for (int j = 0; j < 9; ++j) wd[j] = wsrc[j];

  const int y0 = band * 32;
  #pragma unroll 2
  for (int r = 0; r < 34; ++r) {
    int y = y0 - 1 + r;
    f16 v = (f16)0.f;
    if (y >= 0 && y < 256) v = src[y*256 + tid];
    tile[r][1 + tid] = v;
    if (tid < 2) tile[r][tid ? 257 : 0] = (f16)0.f;
  }
  __syncthreads();

  for (int yy = 0; yy < 32; ++yy) {
    float s = 0.f;
    #pragma unroll
    for (int dy = 0; dy < 3; ++dy)
      #pragma unroll
      for (int dx = 0; dx < 3; ++dx)
        s += wd[dy*3 + dx] * (float)tile[yy + dy][tid + dx];
    int y = y0 + yy;
    if (isv) dst[y*256 + tid] = (f16)s;
    else     dst[y*256 + tid] = (f16)my_gelu(s);
  }
}

// ---------------------------------------------------------------------------
// K2b: depthwise 3x3 for q,k of one head + fused gram partials (qq,kk,qk).
// Rewritten: no int division, uint4 staging, NBAND=32 bands of 8 rows.
// ring[ch][slot][264]: data at f16 idx [4..259], halo zeros at [3],[260].
// GRP layout: [b][h][band][80]. grid = nb*8*NBAND
// ---------------------------------------------------------------------------
__global__ __launch_bounds__(256) void k2b_qk(
    const f16* __restrict__ A, const float* __restrict__ w_qkv_dw,
    float* __restrict__ GRP)
{
  __shared__ f16 ring[16][3][264];
  __shared__ float wq[16][9];
  __shared__ float red[4][80];
  const int tid = threadIdx.x, blk = blockIdx.x;
  const int band = blk & (NBAND-1), h = (blk >> 5) & 7, b = blk >> 8;

  for (int idx = tid; idx < 144; idx += 256) {
    int ch = idx / 9, j = idx % 9;
    int row = (ch < 8) ? (h*8 + ch) : (64 + h*8 + (ch - 8));
    wq[ch][j] = w_qkv_dw[row*9 + j];
  }

  const f16* qbase = A + ((long long)b*256 + 64  + h*8) * HW;
  const f16* kbase = A + ((long long)b*256 + 128 + h*8) * HW;

  // per-thread staging assignment (no division):
  // i=0: cid=tid, i=1: cid=tid+256; ch=cid>>5 (0..15), ck=cid&31 (16B chunk)
  const int y0 = band * 8;
  auto stage = [&](int yy) {
    int slot = (yy + 3) % 3;
    #pragma unroll
    for (int i = 0; i < 2; ++i) {
      int cid = tid + (i << 8);
      int ch = cid >> 5, ck = cid & 31;
      uint4 v = make_uint4(0u, 0u, 0u, 0u);
      if (yy >= 0 && yy < 256) {
        const f16* p = (ch < 8 ? qbase + ch*HW : kbase + (ch-8)*HW)
                     + yy*256 + ck*8;
        v = *(const uint4*)p;
      }
      f16* d = &ring[ch][slot][4 + ck*8];
      *(uint2*)(d)     = make_uint2(v.x, v.y);
      *(uint2*)(d + 4) = make_uint2(v.z, v.w);
    }
    if (tid < 16) {
      ring[tid][slot][3]   = (f16)0.f;
      ring[tid][slot][260] = (f16)0.f;
    }
  };

  float aqq[8] = {0}, akk[8] = {0}, aqk[64] = {0};
  stage(y0 - 1); stage(y0);
  for (int y = y0; y < y0 + 8; ++y) {
    __syncthreads();
    stage(y + 1);
    __syncthreads();
    const int xx = tid;
    float qv[8], kv[8];
    #pragma unroll
    for (int ch = 0; ch < 16; ++ch) {
      float s = 0.f;
      #pragma unroll
      for (int dy = -1; dy <= 1; ++dy) {
        const f16* r = ring[ch][(y + dy + 3) % 3];
        #pragma unroll
        for (int dx = 0; dx < 3; ++dx)
          s += wq[ch][(dy+1)*3 + dx] * (float)r[3 + xx + dx];
      }
      if (ch < 8) qv[ch] = s; else kv[ch - 8] = s;
    }
    #pragma unroll
    for (int cc = 0; cc < 8; ++cc) {
      aqq[cc] += qv[cc]*qv[cc];
      akk[cc] += kv[cc]*kv[cc];
      #pragma unroll
      for (int dd = 0; dd < 8; ++dd)
        aqk[cc*8 + dd] += qv[cc]*kv[dd];
    }
  }
  __syncthreads();
  const int wave = tid >> 6, lane = tid & 63;
  #pragma unroll
  for (int i = 0; i < 80; ++i) {
    float v = (i < 8) ? aqq[i] : (i < 16 ? akk[i-8] : aqk[i-16]);
    #pragma unroll
    for (int off = 32; off; off >>= 1) v += __shfl_xor(v, off);
    if (lane == 0) red[wave][i] = v;
  }
  __syncthreads();
  for (int i = tid; i < 80; i += 256) {
    float v = red[0][i] + red[1][i] + red[2][i] + red[3][i];
    GRP[(((b*8 + h)*NBAND + band) * 80) + i] = v;
  }
}

// ---------------------------------------------------------------------------
// K2c: reduce band partials, normalize, temperature, softmax. grid = nb*8
// ---------------------------------------------------------------------------
__global__ __launch_bounds__(64) void k2c_attn(
    const float* __restrict__ GRP, const float* __restrict__ temp,
    float* __restrict__ ATT)
{
  __shared__ float s[80];
  const int tid = threadIdx.x;
  const int h = blockIdx.x & 7, b = blockIdx.x >> 3;
  for (int i = tid; i < 80; i += 64) {
    float v = 0.f;
    for (int band = 0; band < NBAND; ++band)
      v += GRP[(((b*8 + h)*NBAND + band) * 80) + i];
    s[i] = v;
  }
  __syncthreads();
  const int c = tid >> 3, d = tid & 7;
  float nq = fmaxf(sqrtf(s[c]), 1e-12f);
  float nk = fmaxf(sqrtf(s[8 + d]), 1e-12f);
  float logit = s[16 + c*8 + d] / (nq * nk) * temp[h];
  float m = logit;
  #pragma unroll
  for (int off = 4; off; off >>= 1) m = fmaxf(m, __shfl_xor(m, off));
  float e = __expf(logit - m);
  float sum = e;
  #pragma unroll
  for (int off = 4; off; off >>= 1) sum += __shfl_xor(sum, off);
  ATT[((b*8 + h)*8 + c)*8 + d] = e / sum;
}

// ---------------------------------------------------------------------------
// K3: out = conv1x1( gelu(gate) * (attn @ v), w_proj ). grid = nb*256. f32 out.
// ---------------------------------------------------------------------------
__global__ __launch_bounds__(256) void k3_out(
    const f16* __restrict__ Vv, const f16* __restrict__ GG,
    const float* __restrict__ ATT, const float* __restrict__ w_proj,
    float* __restrict__ out)
{
  __shared__ float attn_s[512];
  __shared__ float wp[4096];
  const int tid = threadIdx.x;
  const int y = blockIdx.x & 255, b = blockIdx.x >> 8;
  for (int i = tid; i < 512; i += 256) attn_s[i] = ATT[b*512 + i];
  for (int i = tid; i < 4096; i += 256) wp[i] = w_proj[i];
  __syncthreads();

  const int xx = tid;
  const long long pos = (long long)y*256 + xx;
  float g[64];
  #pragma unroll
  for (int hd = 0; hd < 8; ++hd) {
    float vv[8];
    #pragma unroll
    for (int d = 0; d < 8; ++d)
      vv[d] = (float)Vv[((long long)b*64 + hd*8 + d)*HW + pos];
    #pragma unroll
    for (int c = 0; c < 8; ++c) {
      float av = 0.f;
      #pragma unroll
      for (int d = 0; d < 8; ++d)
        av += attn_s[hd*64 + c*8 + d] * vv[d];
      float gg = (float)GG[((long long)b*64 + hd*8 + c)*HW + pos];
      g[hd*8 + c] = gg * av;
    }
  }
  for (int co = 0; co < 64; ++co) {
    float acc = 0.f;
    const float4* wr = (const float4*)(wp + co*64);
    #pragma unroll
    for (int q4 = 0; q4 < 16; ++q4) {
      float4 wv = wr[q4];
      acc += wv.x * g[q4*4 + 0] + wv.y * g[q4*4 + 1]
           + wv.z * g[q4*4 + 2] + wv.w * g[q4*4 + 3];
    }
    out[((long long)b*64 + co)*HW + pos] = acc;
  }
}

// ---------------------------------------------------------------------------
extern "C" void kernel_launch(void* const* d_in, const int* in_sizes, int n_in,
                              void* d_out, int out_size, void* d_ws, size_t ws_size,
                              hipStream_t stream)
{
  float* out = (float*)d_out;

  int mp[7] = {-1,-1,-1,-1,-1,-1,-1};
  bool ok = (n_in == 7);
  if (ok) {
    int n4 = 0;
    for (int i = 0; i < 7; ++i) {
      long s = in_sizes[i];
      if      (s == 33554432) mp[0] = i;            // x
      else if (s == 576)      mp[2] = i;            // w_gate_dw
      else if (s == 12288)    mp[3] = i;            // w_qkv
      else if (s == 1728)     mp[4] = i;            // w_qkv_dw
      else if (s == 8)        mp[6] = i;            // temperature
      else if (s == 4096)     { if (n4 == 0) mp[1] = i; else mp[5] = i; ++n4; }
    }
    ok = ok && (n4 == 2);
    for (int i = 0; i < 7; ++i) ok = ok && (mp[i] >= 0);
  }
  if (!ok) { k_signal<<<2048,256,0,stream>>>(out, (long long)out_size, 2000.0f); return; }
  if (out_size != 33554432) { k_signal<<<2048,256,0,stream>>>(out, (long long)out_size, 3000.0f); return; }

  const float* x    = (const float*)d_in[mp[0]];
  const float* wg   = (const float*)d_in[mp[1]];
  const float* wgd  = (const float*)d_in[mp[2]];
  const float* wqkv = (const float*)d_in[mp[3]];
  const float* wqd  = (const float*)d_in[mp[4]];
  const float* wpj  = (const float*)d_in[mp[5]];
  const float* tp   = (const float*)d_in[mp[6]];

  unsigned char* ws = (unsigned char*)d_ws;
  // A 268,435,456 | Vv 67,108,864 | GG 67,108,864 | GRP 8*8*NBAND*80*4 |
  // ATT 16,384
  const size_t GRP_SZ = 8UL*8*NBAND*80*4;          // 655,360
  const size_t FULL = 402653184UL + GRP_SZ + 16384UL;
  const size_t PERB_GRP = 8UL*NBAND*80*4;          // 81,920
  const size_t PERB = 50331648UL + PERB_GRP + 2048UL;

  if (ws != nullptr && ws_size >= FULL) {
    f16*   A    = (f16*)ws;
    f16*   Vv   = (f16*)(ws + 268435456UL);
    f16*   GG   = (f16*)(ws + 335544320UL);
    float* GRP  = (float*)(ws + 402653184UL);
    float* ATT  = (float*)(ws + 402653184UL + GRP_SZ);
    k1_mfma <<<8192, 256, 0, stream>>>(x, wg, wqkv, A);
    k2a_dw  <<<8192, 256, 0, stream>>>(A, wgd, wqd, Vv, GG);
    k2b_qk  <<<8*8*NBAND, 256, 0, stream>>>(A, wqd, GRP);
    k2c_attn<<<64,   64,  0, stream>>>(GRP, tp, ATT);
    k3_out  <<<2048, 256, 0, stream>>>(Vv, GG, ATT, wpj, out);
  } else if (ws != nullptr && ws_size >= PERB) {
    f16*   A    = (f16*)ws;
    f16*   Vv   = (f16*)(ws + 33554432UL);
    f16*   GG   = (f16*)(ws + 41943040UL);
    float* GRP  = (float*)(ws + 50331648UL);
    float* ATT  = (float*)(ws + 50331648UL + PERB_GRP);
    for (int b = 0; b < 8; ++b) {
      const float* xb = x + (long long)b*64*HW;
      float* ob = out + (long long)b*64*HW;
      k1_mfma <<<1024, 256, 0, stream>>>(xb, wg, wqkv, A);
      k2a_dw  <<<1024, 256, 0, stream>>>(A, wgd, wqd, Vv, GG);
      k2b_qk  <<<8*NBAND, 256, 0, stream>>>(A, wqd, GRP);
      k2c_attn<<<8,    64,  0, stream>>>(GRP, tp, ATT);
      k3_out  <<<256,  256, 0, stream>>>(Vv, GG, ATT, wpj, ob);
    }
  } else {
    k_signal<<<2048,256,0,stream>>>(out, (long long)out_size, 1000.0f);
  }
}

// Round 9
// 664.711 us; speedup vs baseline: 2.1486x; 1.3739x over previous
//
#include <hip/hip_runtime.h>

typedef _Float16 f16;
using f16x8 = __attribute__((ext_vector_type(8))) _Float16;
using f32x4 = __attribute__((ext_vector_type(4))) float;

#define HW 65536
#define NBAND 16
#define ROWS 16
#define RS 320   // ring row stride in f16 (multiple of 64 -> XOR-swizzle safe)

// own erf (A&S 7.1.26, |err| <= 1.5e-7); __expf is HW v_exp_f32
static __device__ __forceinline__ float my_erf(float v) {
  float x = fabsf(v);
  float t = 1.f / (1.f + 0.3275911f * x);
  float y = t * (0.254829592f + t * (-0.284496736f + t * (1.421413741f
          + t * (-1.453152027f + t * 1.061405429f))));
  float r = 1.f - y * __expf(-x * x);
  return v < 0.f ? -r : r;
}
static __device__ __forceinline__ float my_gelu(float s) {
  return 0.5f * s * (1.f + my_erf(s * 0.70710678118654752f));
}

__global__ void TRA_Attention_15281493639325_kernel() {}

__global__ void k_signal(float* out, long long n, float val) {
  long long i = (long long)blockIdx.x * blockDim.x + threadIdx.x;
  long long stride = (long long)gridDim.x * blockDim.x;
  for (; i < n; i += stride) out[i] = val;
}

// ---------------------------------------------------------------------------
// K1 (MFMA f16): fused 1x1 conv, 256 out ch. Tile M=256 x N=64 pos, K=64.
// grid = nb*1024. LDS 40KB, XOR-swizzled 16B chunks.
// ---------------------------------------------------------------------------
__global__ __launch_bounds__(256) void k1_mfma(
    const float* __restrict__ x, const float* __restrict__ w_gate,
    const float* __restrict__ w_qkv, f16* __restrict__ A)
{
  __shared__ __align__(16) unsigned char lds[256*128 + 64*128];
  unsigned char* wl = lds;
  unsigned char* xs = lds + 256*128;

  const int tid = threadIdx.x, blk = blockIdx.x;
  const int b = blk >> 10;
  const long long p0 = (long long)(blk & 1023) * 64;

  for (int cid = tid; cid < 4096; cid += 256) {
    int m = cid >> 4, kc = cid & 15;
    const float* src = (m < 64) ? (w_gate + m*64 + kc*4)
                                : (w_qkv + (m-64)*64 + kc*4);
    float4 f = *(const float4*)src;
    int hm = ((m & 7) ^ ((m >> 3) & 7)) << 4;
    f16* dst = (f16*)(wl + m*128 + ((kc*8) ^ hm));
    dst[0]=(f16)f.x; dst[1]=(f16)f.y; dst[2]=(f16)f.z; dst[3]=(f16)f.w;
  }
  for (int cid = tid; cid < 1024; cid += 256) {
    int k = cid >> 4, c = cid & 15;
    float4 f = *(const float4*)(x + ((long long)b*64 + k)*HW + p0 + c*4);
    const float* e = (const float*)&f;
    #pragma unroll
    for (int i = 0; i < 4; ++i) {
      int p = c*4 + i;
      int hp = ((p & 7) ^ ((p >> 3) & 7)) << 4;
      *(f16*)(xs + p*128 + ((2*k) ^ hp)) = (f16)e[i];
    }
  }
  __syncthreads();

  const int wave = tid >> 6, lane = tid & 63;
  const int m0 = (wave >> 1) * 128, n0 = (wave & 1) * 32;
  const int lr = lane & 15, lg = lane >> 4;

  f32x4 acc[8][2];
  #pragma unroll
  for (int i = 0; i < 8; ++i)
    #pragma unroll
    for (int j = 0; j < 2; ++j) acc[i][j] = (f32x4){0.f,0.f,0.f,0.f};

  #pragma unroll
  for (int ks = 0; ks < 2; ++ks) {
    f16x8 af[8], bfr[2];
    #pragma unroll
    for (int mi = 0; mi < 8; ++mi) {
      int m = m0 + mi*16 + lr;
      int hm = ((m & 7) ^ ((m >> 3) & 7)) << 4;
      af[mi] = *(const f16x8*)(wl + m*128 + ((ks*64 + lg*16) ^ hm));
    }
    #pragma unroll
    for (int ni = 0; ni < 2; ++ni) {
      int p = n0 + ni*16 + lr;
      int hp = ((p & 7) ^ ((p >> 3) & 7)) << 4;
      bfr[ni] = *(const f16x8*)(xs + p*128 + ((ks*64 + lg*16) ^ hp));
    }
    #pragma unroll
    for (int mi = 0; mi < 8; ++mi)
      #pragma unroll
      for (int ni = 0; ni < 2; ++ni)
        acc[mi][ni] = __builtin_amdgcn_mfma_f32_16x16x32_f16(
            af[mi], bfr[ni], acc[mi][ni], 0, 0, 0);
  }

  #pragma unroll
  for (int mi = 0; mi < 8; ++mi)
    #pragma unroll
    for (int ni = 0; ni < 2; ++ni)
      #pragma unroll
      for (int r = 0; r < 4; ++r) {
        int m = m0 + mi*16 + lg*4 + r;
        long long p = p0 + n0 + ni*16 + lr;
        A[((long long)b*256 + m)*HW + p] = (f16)acc[mi][ni][r];
      }
}

// ---------------------------------------------------------------------------
// K2a: depthwise 3x3 for gate (+ GELU) and v channels. 1 barrier. grid=nb*1024
// ---------------------------------------------------------------------------
__global__ __launch_bounds__(256) void k2a_dw(
    const f16* __restrict__ A, const float* __restrict__ w_gate_dw,
    const float* __restrict__ w_qkv_dw, f16* __restrict__ Vv, f16* __restrict__ GG)
{
  __shared__ f16 tile[34][258];
  const int tid = threadIdx.x, blk = blockIdx.x;
  const int band = blk & 7, ch2 = (blk >> 3) & 127, b = blk >> 10;
  const bool isv = ch2 >= 64;
  const int c = isv ? ch2 - 64 : ch2;
  const f16* src = A + ((long long)b*256 + (isv ? 192 + c : c)) * HW;
  const float* wsrc = isv ? (w_qkv_dw + (128 + c)*9) : (w_gate_dw + c*9);
  f16* dst = (isv ? Vv : GG) + ((long long)b*64 + c) * HW;

  float wd[9];
  #pragma unroll
  for (int j = 0; j < 9; ++j) wd[j] = wsrc[j];

  const int y0 = band * 32;
  #pragma unroll 2
  for (int r = 0; r < 34; ++r) {
    int y = y0 - 1 + r;
    f16 v = (f16)0.f;
    if (y >= 0 && y < 256) v = src[y*256 + tid];
    tile[r][1 + tid] = v;
    if (tid < 2) tile[r][tid ? 257 : 0] = (f16)0.f;
  }
  __syncthreads();

  for (int yy = 0; yy < 32; ++yy) {
    float s = 0.f;
    #pragma unroll
    for (int dy = 0; dy < 3; ++dy)
      #pragma unroll
      for (int dx = 0; dx < 3; ++dx)
        s += wd[dy*3 + dx] * (float)tile[yy + dy][tid + dx];
    int y = y0 + yy;
    if (isv) dst[y*256 + tid] = (f16)s;
    else     dst[y*256 + tid] = (f16)my_gelu(s);
  }
}

// ---------------------------------------------------------------------------
// K2b (MFMA gram): depthwise 3x3 for q,k of one head fused with the full
// 16x16 gram G = M·M^T (M = [q0..q7,k0..k7] x positions) via
// mfma_f32_16x16x32_f16 with IDENTICAL A/B fragments.
// One wave (64 thr) per (b,h,band of 16 rows). grid = nb*8*NBAND.
// Lane l: channel c=l&15, position-subchunk g=l>>4. Per 32-pos chunk the lane
// computes its 8 conv outputs straight into its fragment (layout proven by k1).
// A-rows staged in 4-slot LDS ring, XOR-swizzled, prefetch 2 rows ahead (T14).
// GRP layout: [b][h][band][80] = qq[8], kk[8], qk[64].
// ---------------------------------------------------------------------------
__device__ __forceinline__ int ridx(int c, int slot, int i) {
  return ((((c << 2) | slot) * RS) + i) ^ ((c & 7) << 3);
}

__global__ __launch_bounds__(64) void k2b_qk(
    const f16* __restrict__ A, const float* __restrict__ w_qkv_dw,
    float* __restrict__ GRP)
{
  __shared__ __align__(16) f16 ring[16*4*RS];  // 40,960 B
  const int lane = threadIdx.x, blk = blockIdx.x;
  const int band = blk & (NBAND-1), h = (blk >> 4) & 7, b = blk >> 7;

  const int c  = lane & 15, g  = lane >> 4;   // compute role
  const int cs = lane >> 2, q4 = lane & 3;    // staging role

  // per-lane dwconv weights for channel c (q: dw rows 0..63, k: 64..127)
  const int wrow = (c < 8) ? (h*8 + c) : (64 + h*8 + (c - 8));
  float wq[9];
  #pragma unroll
  for (int j = 0; j < 9; ++j) wq[j] = w_qkv_dw[wrow*9 + j];

  // staging source for channel cs (A: q at ch 64.., k at ch 128..)
  const f16* sbase = A + ((long long)b*256 +
      (cs < 8 ? 64 + h*8 + cs : 128 + h*8 + (cs - 8))) * HW;

  // zero halos: idx 7 (x=-1) and 264 (x=256), all (cs, slot=q4)
  ring[ridx(cs, q4, 7)]   = (f16)0.f;
  ring[ridx(cs, q4, 264)] = (f16)0.f;

  auto load_row = [&](int yy, uint4* r) {
    if (yy >= 0 && yy < 256) {
      const f16* p = sbase + yy*256 + q4*64;
      #pragma unroll
      for (int t = 0; t < 8; ++t) r[t] = *(const uint4*)(p + t*8);
    } else {
      #pragma unroll
      for (int t = 0; t < 8; ++t) r[t] = make_uint4(0u,0u,0u,0u);
    }
  };
  auto write_row = [&](int slot, const uint4* r) {
    #pragma unroll
    for (int t = 0; t < 8; ++t)
      *(uint4*)&ring[ridx(cs, slot, 8 + q4*64 + t*8)] = r[t];
  };

  const int y0 = band * ROWS;
  {
    uint4 r[8];
    load_row(y0-1, r); write_row((y0+3)&3, r);
    load_row(y0,   r); write_row((y0+4)&3, r);
    load_row(y0+1, r); write_row((y0+5)&3, r);
  }
  __syncthreads();

  f32x4 acc = (f32x4){0.f, 0.f, 0.f, 0.f};

  for (int y = y0; y < y0 + ROWS; ++y) {
    uint4 r[8];
    const bool pf = (y + 2 <= y0 + ROWS);
    if (pf) load_row(y + 2, r);              // issue early (T14)

    const int s0 = (y+3)&3, s1 = (y+4)&3, s2 = (y+5)&3;
    #pragma unroll
    for (int q = 0; q < 8; ++q) {
      const int base = 7 + q*32 + g*8;       // idx of x0-1 tap
      float v0[10], v1[10], v2[10];
      #pragma unroll
      for (int t = 0; t < 10; ++t) {
        v0[t] = (float)ring[ridx(c, s0, base+t)];
        v1[t] = (float)ring[ridx(c, s1, base+t)];
        v2[t] = (float)ring[ridx(c, s2, base+t)];
      }
      f16x8 frag;
      #pragma unroll
      for (int j = 0; j < 8; ++j) {
        float s = wq[0]*v0[j] + wq[1]*v0[j+1] + wq[2]*v0[j+2]
                + wq[3]*v1[j] + wq[4]*v1[j+1] + wq[5]*v1[j+2]
                + wq[6]*v2[j] + wq[7]*v2[j+1] + wq[8]*v2[j+2];
        frag[j] = (f16)s;
      }
      acc = __builtin_amdgcn_mfma_f32_16x16x32_f16(frag, frag, acc, 0, 0, 0);
    }
    if (pf) write_row((y+6)&3, r);           // write late, after reads
    __syncthreads();
  }

  // D layout: col = lane&15, row = (lane>>4)*4 + reg  -> extract 80 values
  const long long gbase = (long long)((b*8 + h)*NBAND + band) * 80;
  #pragma unroll
  for (int reg = 0; reg < 4; ++reg) {
    int rrow = g*4 + reg;
    float val = acc[reg];
    if (rrow == c) GRP[gbase + c] = val;                          // qq / kk
    else if (rrow < 8 && c >= 8) GRP[gbase + 16 + rrow*8 + (c-8)] = val;  // qk
  }
}

// ---------------------------------------------------------------------------
// K2c: reduce band partials, normalize, temperature, softmax. grid = nb*8
// ---------------------------------------------------------------------------
__global__ __launch_bounds__(64) void k2c_attn(
    const float* __restrict__ GRP, const float* __restrict__ temp,
    float* __restrict__ ATT)
{
  __shared__ float s[80];
  const int tid = threadIdx.x;
  const int h = blockIdx.x & 7, b = blockIdx.x >> 3;
  for (int i = tid; i < 80; i += 64) {
    float v = 0.f;
    for (int band = 0; band < NBAND; ++band)
      v += GRP[(((b*8 + h)*NBAND + band) * 80) + i];
    s[i] = v;
  }
  __syncthreads();
  const int c = tid >> 3, d = tid & 7;
  float nq = fmaxf(sqrtf(s[c]), 1e-12f);
  float nk = fmaxf(sqrtf(s[8 + d]), 1e-12f);
  float logit = s[16 + c*8 + d] / (nq * nk) * temp[h];
  float m = logit;
  #pragma unroll
  for (int off = 4; off; off >>= 1) m = fmaxf(m, __shfl_xor(m, off));
  float e = __expf(logit - m);
  float sum = e;
  #pragma unroll
  for (int off = 4; off; off >>= 1) sum += __shfl_xor(sum, off);
  ATT[((b*8 + h)*8 + c)*8 + d] = e / sum;
}

// ---------------------------------------------------------------------------
// K3: out = conv1x1( gelu(gate) * (attn @ v), w_proj ). grid = nb*256. f32 out.
// ---------------------------------------------------------------------------
__global__ __launch_bounds__(256) void k3_out(
    const f16* __restrict__ Vv, const f16* __restrict__ GG,
    const float* __restrict__ ATT, const float* __restrict__ w_proj,
    float* __restrict__ out)
{
  __shared__ float attn_s[512];
  __shared__ float wp[4096];
  const int tid = threadIdx.x;
  const int y = blockIdx.x & 255, b = blockIdx.x >> 8;
  for (int i = tid; i < 512; i += 256) attn_s[i] = ATT[b*512 + i];
  for (int i = tid; i < 4096; i += 256) wp[i] = w_proj[i];
  __syncthreads();

  const int xx = tid;
  const long long pos = (long long)y*256 + xx;
  float g[64];
  #pragma unroll
  for (int hd = 0; hd < 8; ++hd) {
    float vv[8];
    #pragma unroll
    for (int d = 0; d < 8; ++d)
      vv[d] = (float)Vv[((long long)b*64 + hd*8 + d)*HW + pos];
    #pragma unroll
    for (int c = 0; c < 8; ++c) {
      float av = 0.f;
      #pragma unroll
      for (int d = 0; d < 8; ++d)
        av += attn_s[hd*64 + c*8 + d] * vv[d];
      float gg = (float)GG[((long long)b*64 + hd*8 + c)*HW + pos];
      g[hd*8 + c] = gg * av;
    }
  }
  for (int co = 0; co < 64; ++co) {
    float acc = 0.f;
    const float4* wr = (const float4*)(wp + co*64);
    #pragma unroll
    for (int q4 = 0; q4 < 16; ++q4) {
      float4 wv = wr[q4];
      acc += wv.x * g[q4*4 + 0] + wv.y * g[q4*4 + 1]
           + wv.z * g[q4*4 + 2] + wv.w * g[q4*4 + 3];
    }
    out[((long long)b*64 + co)*HW + pos] = acc;
  }
}

// ---------------------------------------------------------------------------
extern "C" void kernel_launch(void* const* d_in, const int* in_sizes, int n_in,
                              void* d_out, int out_size, void* d_ws, size_t ws_size,
                              hipStream_t stream)
{
  float* out = (float*)d_out;

  int mp[7] = {-1,-1,-1,-1,-1,-1,-1};
  bool ok = (n_in == 7);
  if (ok) {
    int n4 = 0;
    for (int i = 0; i < 7; ++i) {
      long s = in_sizes[i];
      if      (s == 33554432) mp[0] = i;            // x
      else if (s == 576)      mp[2] = i;            // w_gate_dw
      else if (s == 12288)    mp[3] = i;            // w_qkv
      else if (s == 1728)     mp[4] = i;            // w_qkv_dw
      else if (s == 8)        mp[6] = i;            // temperature
      else if (s == 4096)     { if (n4 == 0) mp[1] = i; else mp[5] = i; ++n4; }
    }
    ok = ok && (n4 == 2);
    for (int i = 0; i < 7; ++i) ok = ok && (mp[i] >= 0);
  }
  if (!ok) { k_signal<<<2048,256,0,stream>>>(out, (long long)out_size, 2000.0f); return; }
  if (out_size != 33554432) { k_signal<<<2048,256,0,stream>>>(out, (long long)out_size, 3000.0f); return; }

  const float* x    = (const float*)d_in[mp[0]];
  const float* wg   = (const float*)d_in[mp[1]];
  const float* wgd  = (const float*)d_in[mp[2]];
  const float* wqkv = (const float*)d_in[mp[3]];
  const float* wqd  = (const float*)d_in[mp[4]];
  const float* wpj  = (const float*)d_in[mp[5]];
  const float* tp   = (const float*)d_in[mp[6]];

  unsigned char* ws = (unsigned char*)d_ws;
  // A 268,435,456 | Vv 67,108,864 | GG 67,108,864 | GRP | ATT
  const size_t GRP_SZ   = 8UL*8*NBAND*80*4;        // 327,680
  const size_t FULL     = 402653184UL + GRP_SZ + 16384UL;
  const size_t PERB_GRP = 8UL*NBAND*80*4;          // 40,960
  const size_t PERB     = 50331648UL + PERB_GRP + 2048UL;

  if (ws != nullptr && ws_size >= FULL) {
    f16*   A    = (f16*)ws;
    f16*   Vv   = (f16*)(ws + 268435456UL);
    f16*   GG   = (f16*)(ws + 335544320UL);
    float* GRP  = (float*)(ws + 402653184UL);
    float* ATT  = (float*)(ws + 402653184UL + GRP_SZ);
    k1_mfma <<<8192, 256, 0, stream>>>(x, wg, wqkv, A);
    k2a_dw  <<<8192, 256, 0, stream>>>(A, wgd, wqd, Vv, GG);
    k2b_qk  <<<8*8*NBAND, 64, 0, stream>>>(A, wqd, GRP);
    k2c_attn<<<64,   64,  0, stream>>>(GRP, tp, ATT);
    k3_out  <<<2048, 256, 0, stream>>>(Vv, GG, ATT, wpj, out);
  } else if (ws != nullptr && ws_size >= PERB) {
    f16*   A    = (f16*)ws;
    f16*   Vv   = (f16*)(ws + 33554432UL);
    f16*   GG   = (f16*)(ws + 41943040UL);
    float* GRP  = (float*)(ws + 50331648UL);
    float* ATT  = (float*)(ws + 50331648UL + PERB_GRP);
    for (int b = 0; b < 8; ++b) {
      const float* xb = x + (long long)b*64*HW;
      float* ob = out + (long long)b*64*HW;
      k1_mfma <<<1024, 256, 0, stream>>>(xb, wg, wqkv, A);
      k2a_dw  <<<1024, 256, 0, stream>>>(A, wgd, wqd, Vv, GG);
      k2b_qk  <<<8*NBAND, 64, 0, stream>>>(A, wqd, GRP);
      k2c_attn<<<8,    64,  0, stream>>>(GRP, tp, ATT);
      k3_out  <<<256,  256, 0, stream>>>(Vv, GG, ATT, wpj, ob);
    }
  } else {
    k_signal<<<2048,256,0,stream>>>(out, (long long)out_size, 1000.0f);
  }
}

// Round 10
// 460.328 us; speedup vs baseline: 3.1025x; 1.4440x over previous
//
#include <hip/hip_runtime.h>

typedef _Float16 f16;
using f16x8 = __attribute__((ext_vector_type(8))) _Float16;
using f32x4 = __attribute__((ext_vector_type(4))) float;

#define HW 65536
#define NBAND 16
#define ROWS 16
#define RS 320   // k2b ring row stride in f16

// own erf (A&S 7.1.26, |err| <= 1.5e-7); __expf is HW v_exp_f32
static __device__ __forceinline__ float my_erf(float v) {
  float x = fabsf(v);
  float t = 1.f / (1.f + 0.3275911f * x);
  float y = t * (0.254829592f + t * (-0.284496736f + t * (1.421413741f
          + t * (-1.453152027f + t * 1.061405429f))));
  float r = 1.f - y * __expf(-x * x);
  return v < 0.f ? -r : r;
}
static __device__ __forceinline__ float my_gelu(float s) {
  return 0.5f * s * (1.f + my_erf(s * 0.70710678118654752f));
}

__global__ void TRA_Attention_15281493639325_kernel() {}

__global__ void k_signal(float* out, long long n, float val) {
  long long i = (long long)blockIdx.x * blockDim.x + threadIdx.x;
  long long stride = (long long)gridDim.x * blockDim.x;
  for (; i < n; i += stride) out[i] = val;
}

// ---------------------------------------------------------------------------
// K1 (MFMA f16): fused 1x1 conv, 256 out ch. Tile M=256 x N=64 pos, K=64.
// grid = nb*1024. LDS 40KB, XOR-swizzled 16B chunks.
// ---------------------------------------------------------------------------
__global__ __launch_bounds__(256) void k1_mfma(
    const float* __restrict__ x, const float* __restrict__ w_gate,
    const float* __restrict__ w_qkv, f16* __restrict__ A)
{
  __shared__ __align__(16) unsigned char lds[256*128 + 64*128];
  unsigned char* wl = lds;
  unsigned char* xs = lds + 256*128;

  const int tid = threadIdx.x, blk = blockIdx.x;
  const int b = blk >> 10;
  const long long p0 = (long long)(blk & 1023) * 64;

  for (int cid = tid; cid < 4096; cid += 256) {
    int m = cid >> 4, kc = cid & 15;
    const float* src = (m < 64) ? (w_gate + m*64 + kc*4)
                                : (w_qkv + (m-64)*64 + kc*4);
    float4 f = *(const float4*)src;
    int hm = ((m & 7) ^ ((m >> 3) & 7)) << 4;
    f16* dst = (f16*)(wl + m*128 + ((kc*8) ^ hm));
    dst[0]=(f16)f.x; dst[1]=(f16)f.y; dst[2]=(f16)f.z; dst[3]=(f16)f.w;
  }
  for (int cid = tid; cid < 1024; cid += 256) {
    int k = cid >> 4, c = cid & 15;
    float4 f = *(const float4*)(x + ((long long)b*64 + k)*HW + p0 + c*4);
    const float* e = (const float*)&f;
    #pragma unroll
    for (int i = 0; i < 4; ++i) {
      int p = c*4 + i;
      int hp = ((p & 7) ^ ((p >> 3) & 7)) << 4;
      *(f16*)(xs + p*128 + ((2*k) ^ hp)) = (f16)e[i];
    }
  }
  __syncthreads();

  const int wave = tid >> 6, lane = tid & 63;
  const int m0 = (wave >> 1) * 128, n0 = (wave & 1) * 32;
  const int lr = lane & 15, lg = lane >> 4;

  f32x4 acc[8][2];
  #pragma unroll
  for (int i = 0; i < 8; ++i)
    #pragma unroll
    for (int j = 0; j < 2; ++j) acc[i][j] = (f32x4){0.f,0.f,0.f,0.f};

  #pragma unroll
  for (int ks = 0; ks < 2; ++ks) {
    f16x8 af[8], bfr[2];
    #pragma unroll
    for (int mi = 0; mi < 8; ++mi) {
      int m = m0 + mi*16 + lr;
      int hm = ((m & 7) ^ ((m >> 3) & 7)) << 4;
      af[mi] = *(const f16x8*)(wl + m*128 + ((ks*64 + lg*16) ^ hm));
    }
    #pragma unroll
    for (int ni = 0; ni < 2; ++ni) {
      int p = n0 + ni*16 + lr;
      int hp = ((p & 7) ^ ((p >> 3) & 7)) << 4;
      bfr[ni] = *(const f16x8*)(xs + p*128 + ((ks*64 + lg*16) ^ hp));
    }
    #pragma unroll
    for (int mi = 0; mi < 8; ++mi)
      #pragma unroll
      for (int ni = 0; ni < 2; ++ni)
        acc[mi][ni] = __builtin_amdgcn_mfma_f32_16x16x32_f16(
            af[mi], bfr[ni], acc[mi][ni], 0, 0, 0);
  }

  #pragma unroll
  for (int mi = 0; mi < 8; ++mi)
    #pragma unroll
    for (int ni = 0; ni < 2; ++ni)
      #pragma unroll
      for (int r = 0; r < 4; ++r) {
        int m = m0 + mi*16 + lg*4 + r;
        long long p = p0 + n0 + ni*16 + lr;
        A[((long long)b*256 + m)*HW + p] = (f16)acc[mi][ni][r];
      }
}

// ---------------------------------------------------------------------------
// K2a (reg-rolling, LDS-free): depthwise 3x3 for gate (+GELU) and v channels.
// Thread = 8-wide x-chunk (uint4 f16x8 loads) x 8-row strip; x-halo via
// __shfl(lane+-1); 3-row float window in registers, fully unrolled.
// grid = nb*128ch*4 ybands, 256 thr (32 x-chunks x 8 y-subgroups).
// ---------------------------------------------------------------------------
__global__ __launch_bounds__(256) void k2a_dw(
    const f16* __restrict__ A, const float* __restrict__ w_gate_dw,
    const float* __restrict__ w_qkv_dw, f16* __restrict__ Vv, f16* __restrict__ GG)
{
  const int tid = threadIdx.x, blk = blockIdx.x;
  const int yband = blk & 3, ch2 = (blk >> 2) & 127, b = blk >> 9;
  const bool isv = ch2 >= 64;
  const int c = isv ? ch2 - 64 : ch2;
  const f16* src = A + ((long long)b*256 + (isv ? 192 + c : c)) * HW;
  const float* wsrc = isv ? (w_qkv_dw + (128 + c)*9) : (w_gate_dw + c*9);
  f16* dst = (isv ? Vv : GG) + ((long long)b*64 + c) * HW;

  float wd[9];
  #pragma unroll
  for (int j = 0; j < 9; ++j) wd[j] = wsrc[j];

  const int xc = tid & 31, ysub = tid >> 5;
  const int lane = tid & 63;
  const int xbase = xc * 8;
  const int y0 = yband * 64 + ysub * 8;

  // rowbuf[slot][0..9]: [0]=left halo, [1..8]=chunk, [9]=right halo
  float rb[3][10];

  auto load_row = [&](int y, float* r) {
    if (y >= 0 && y < 256) {
      uint4 raw = *(const uint4*)(src + y*256 + xbase);
      const f16* e = (const f16*)&raw;
      #pragma unroll
      for (int t = 0; t < 8; ++t) r[1 + t] = (float)e[t];
    } else {
      #pragma unroll
      for (int t = 0; t < 8; ++t) r[1 + t] = 0.f;
    }
    float lf = __shfl(r[8], lane - 1);   // lane-1's c7 (uniform exec)
    float rf = __shfl(r[1], lane + 1);   // lane+1's c0
    r[0] = (xc == 0)  ? 0.f : lf;
    r[9] = (xc == 31) ? 0.f : rf;
  };

  load_row(y0 - 1, rb[0]);
  load_row(y0,     rb[1]);

  #pragma unroll
  for (int i = 0; i < 8; ++i) {
    load_row(y0 + i + 1, rb[(i + 2) % 3]);
    const float* rm = rb[i % 3];
    const float* r0 = rb[(i + 1) % 3];
    const float* rp = rb[(i + 2) % 3];
    f16x8 st;
    #pragma unroll
    for (int j = 0; j < 8; ++j) {
      float s = wd[0]*rm[j] + wd[1]*rm[j+1] + wd[2]*rm[j+2]
              + wd[3]*r0[j] + wd[4]*r0[j+1] + wd[5]*r0[j+2]
              + wd[6]*rp[j] + wd[7]*rp[j+1] + wd[8]*rp[j+2];
      if (!isv) s = my_gelu(s);
      st[j] = (f16)s;
    }
    *(f16x8*)(dst + (y0 + i)*256 + xbase) = st;
  }
}

// ---------------------------------------------------------------------------
// K2b (MFMA gram): dwconv for q,k of one head fused with 16x16 gram via
// mfma_f32_16x16x32_f16 with identical A/B fragments. 1 wave per
// (b,h,16-row band). GRP layout: [b][h][band][80] = qq[8], kk[8], qk[64].
// ---------------------------------------------------------------------------
__device__ __forceinline__ int ridx(int c, int slot, int i) {
  return ((((c << 2) | slot) * RS) + i) ^ ((c & 7) << 3);
}

__global__ __launch_bounds__(64) void k2b_qk(
    const f16* __restrict__ A, const float* __restrict__ w_qkv_dw,
    float* __restrict__ GRP)
{
  __shared__ __align__(16) f16 ring[16*4*RS];  // 40,960 B
  const int lane = threadIdx.x, blk = blockIdx.x;
  const int band = blk & (NBAND-1), h = (blk >> 4) & 7, b = blk >> 7;

  const int c  = lane & 15, g  = lane >> 4;   // compute role
  const int cs = lane >> 2, q4 = lane & 3;    // staging role

  const int wrow = (c < 8) ? (h*8 + c) : (64 + h*8 + (c - 8));
  float wq[9];
  #pragma unroll
  for (int j = 0; j < 9; ++j) wq[j] = w_qkv_dw[wrow*9 + j];

  const f16* sbase = A + ((long long)b*256 +
      (cs < 8 ? 64 + h*8 + cs : 128 + h*8 + (cs - 8))) * HW;

  ring[ridx(cs, q4, 7)]   = (f16)0.f;
  ring[ridx(cs, q4, 264)] = (f16)0.f;

  auto load_row = [&](int yy, uint4* r) {
    if (yy >= 0 && yy < 256) {
      const f16* p = sbase + yy*256 + q4*64;
      #pragma unroll
      for (int t = 0; t < 8; ++t) r[t] = *(const uint4*)(p + t*8);
    } else {
      #pragma unroll
      for (int t = 0; t < 8; ++t) r[t] = make_uint4(0u,0u,0u,0u);
    }
  };
  auto write_row = [&](int slot, const uint4* r) {
    #pragma unroll
    for (int t = 0; t < 8; ++t)
      *(uint4*)&ring[ridx(cs, slot, 8 + q4*64 + t*8)] = r[t];
  };

  const int y0 = band * ROWS;
  {
    uint4 r[8];
    load_row(y0-1, r); write_row((y0+3)&3, r);
    load_row(y0,   r); write_row((y0+4)&3, r);
    load_row(y0+1, r); write_row((y0+5)&3, r);
  }
  __syncthreads();

  f32x4 acc = (f32x4){0.f, 0.f, 0.f, 0.f};

  for (int y = y0; y < y0 + ROWS; ++y) {
    uint4 r[8];
    const bool pf = (y + 2 <= y0 + ROWS);
    if (pf) load_row(y + 2, r);              // issue early (T14)

    const int s0 = (y+3)&3, s1 = (y+4)&3, s2 = (y+5)&3;
    #pragma unroll
    for (int q = 0; q < 8; ++q) {
      const int base = 7 + q*32 + g*8;
      float v0[10], v1[10], v2[10];
      #pragma unroll
      for (int t = 0; t < 10; ++t) {
        v0[t] = (float)ring[ridx(c, s0, base+t)];
        v1[t] = (float)ring[ridx(c, s1, base+t)];
        v2[t] = (float)ring[ridx(c, s2, base+t)];
      }
      f16x8 frag;
      #pragma unroll
      for (int j = 0; j < 8; ++j) {
        float s = wq[0]*v0[j] + wq[1]*v0[j+1] + wq[2]*v0[j+2]
                + wq[3]*v1[j] + wq[4]*v1[j+1] + wq[5]*v1[j+2]
                + wq[6]*v2[j] + wq[7]*v2[j+1] + wq[8]*v2[j+2];
        frag[j] = (f16)s;
      }
      acc = __builtin_amdgcn_mfma_f32_16x16x32_f16(frag, frag, acc, 0, 0, 0);
    }
    if (pf) write_row((y+6)&3, r);           // write late
    __syncthreads();
  }

  const long long gbase = (long long)((b*8 + h)*NBAND + band) * 80;
  #pragma unroll
  for (int reg = 0; reg < 4; ++reg) {
    int rrow = g*4 + reg;
    float val = acc[reg];
    if (rrow == c) GRP[gbase + c] = val;
    else if (rrow < 8 && c >= 8) GRP[gbase + 16 + rrow*8 + (c-8)] = val;
  }
}

// ---------------------------------------------------------------------------
// K2c: reduce band partials, normalize, temperature, softmax. grid = nb*8
// ---------------------------------------------------------------------------
__global__ __launch_bounds__(64) void k2c_attn(
    const float* __restrict__ GRP, const float* __restrict__ temp,
    float* __restrict__ ATT)
{
  __shared__ float s[80];
  const int tid = threadIdx.x;
  const int h = blockIdx.x & 7, b = blockIdx.x >> 3;
  for (int i = tid; i < 80; i += 64) {
    float v = 0.f;
    for (int band = 0; band < NBAND; ++band)
      v += GRP[(((b*8 + h)*NBAND + band) * 80) + i];
    s[i] = v;
  }
  __syncthreads();
  const int c = tid >> 3, d = tid & 7;
  float nq = fmaxf(sqrtf(s[c]), 1e-12f);
  float nk = fmaxf(sqrtf(s[8 + d]), 1e-12f);
  float logit = s[16 + c*8 + d] / (nq * nk) * temp[h];
  float m = logit;
  #pragma unroll
  for (int off = 4; off; off >>= 1) m = fmaxf(m, __shfl_xor(m, off));
  float e = __expf(logit - m);
  float sum = e;
  #pragma unroll
  for (int off = 4; off; off >>= 1) sum += __shfl_xor(sum, off);
  ATT[((b*8 + h)*8 + c)*8 + d] = e / sum;
}

// ---------------------------------------------------------------------------
// K3: out = conv1x1( gelu(gate) * (attn @ v), w_proj ). grid = nb*256. f32 out.
// ---------------------------------------------------------------------------
__global__ __launch_bounds__(256) void k3_out(
    const f16* __restrict__ Vv, const f16* __restrict__ GG,
    const float* __restrict__ ATT, const float* __restrict__ w_proj,
    float* __restrict__ out)
{
  __shared__ float attn_s[512];
  __shared__ float wp[4096];
  const int tid = threadIdx.x;
  const int y = blockIdx.x & 255, b = blockIdx.x >> 8;
  for (int i = tid; i < 512; i += 256) attn_s[i] = ATT[b*512 + i];
  for (int i = tid; i < 4096; i += 256) wp[i] = w_proj[i];
  __syncthreads();

  const int xx = tid;
  const long long pos = (long long)y*256 + xx;
  float g[64];
  #pragma unroll
  for (int hd = 0; hd < 8; ++hd) {
    float vv[8];
    #pragma unroll
    for (int d = 0; d < 8; ++d)
      vv[d] = (float)Vv[((long long)b*64 + hd*8 + d)*HW + pos];
    #pragma unroll
    for (int c = 0; c < 8; ++c) {
      float av = 0.f;
      #pragma unroll
      for (int d = 0; d < 8; ++d)
        av += attn_s[hd*64 + c*8 + d] * vv[d];
      float gg = (float)GG[((long long)b*64 + hd*8 + c)*HW + pos];
      g[hd*8 + c] = gg * av;
    }
  }
  for (int co = 0; co < 64; ++co) {
    float acc = 0.f;
    const float4* wr = (const float4*)(wp + co*64);
    #pragma unroll
    for (int q4 = 0; q4 < 16; ++q4) {
      float4 wv = wr[q4];
      acc += wv.x * g[q4*4 + 0] + wv.y * g[q4*4 + 1]
           + wv.z * g[q4*4 + 2] + wv.w * g[q4*4 + 3];
    }
    out[((long long)b*64 + co)*HW + pos] = acc;
  }
}

// ---------------------------------------------------------------------------
extern "C" void kernel_launch(void* const* d_in, const int* in_sizes, int n_in,
                              void* d_out, int out_size, void* d_ws, size_t ws_size,
                              hipStream_t stream)
{
  float* out = (float*)d_out;

  int mp[7] = {-1,-1,-1,-1,-1,-1,-1};
  bool ok = (n_in == 7);
  if (ok) {
    int n4 = 0;
    for (int i = 0; i < 7; ++i) {
      long s = in_sizes[i];
      if      (s == 33554432) mp[0] = i;            // x
      else if (s == 576)      mp[2] = i;            // w_gate_dw
      else if (s == 12288)    mp[3] = i;            // w_qkv
      else if (s == 1728)     mp[4] = i;            // w_qkv_dw
      else if (s == 8)        mp[6] = i;            // temperature
      else if (s == 4096)     { if (n4 == 0) mp[1] = i; else mp[5] = i; ++n4; }
    }
    ok = ok && (n4 == 2);
    for (int i = 0; i < 7; ++i) ok = ok && (mp[i] >= 0);
  }
  if (!ok) { k_signal<<<2048,256,0,stream>>>(out, (long long)out_size, 2000.0f); return; }
  if (out_size != 33554432) { k_signal<<<2048,256,0,stream>>>(out, (long long)out_size, 3000.0f); return; }

  const float* x    = (const float*)d_in[mp[0]];
  const float* wg   = (const float*)d_in[mp[1]];
  const float* wgd  = (const float*)d_in[mp[2]];
  const float* wqkv = (const float*)d_in[mp[3]];
  const float* wqd  = (const float*)d_in[mp[4]];
  const float* wpj  = (const float*)d_in[mp[5]];
  const float* tp   = (const float*)d_in[mp[6]];

  unsigned char* ws = (unsigned char*)d_ws;
  const size_t GRP_SZ   = 8UL*8*NBAND*80*4;
  const size_t FULL     = 402653184UL + GRP_SZ + 16384UL;
  const size_t PERB_GRP = 8UL*NBAND*80*4;
  const size_t PERB     = 50331648UL + PERB_GRP + 2048UL;

  if (ws != nullptr && ws_size >= FULL) {
    f16*   A    = (f16*)ws;
    f16*   Vv   = (f16*)(ws + 268435456UL);
    f16*   GG   = (f16*)(ws + 335544320UL);
    float* GRP  = (float*)(ws + 402653184UL);
    float* ATT  = (float*)(ws + 402653184UL + GRP_SZ);
    k1_mfma <<<8192, 256, 0, stream>>>(x, wg, wqkv, A);
    k2a_dw  <<<4096, 256, 0, stream>>>(A, wgd, wqd, Vv, GG);
    k2b_qk  <<<8*8*NBAND, 64, 0, stream>>>(A, wqd, GRP);
    k2c_attn<<<64,   64,  0, stream>>>(GRP, tp, ATT);
    k3_out  <<<2048, 256, 0, stream>>>(Vv, GG, ATT, wpj, out);
  } else if (ws != nullptr && ws_size >= PERB) {
    f16*   A    = (f16*)ws;
    f16*   Vv   = (f16*)(ws + 33554432UL);
    f16*   GG   = (f16*)(ws + 41943040UL);
    float* GRP  = (float*)(ws + 50331648UL);
    float* ATT  = (float*)(ws + 50331648UL + PERB_GRP);
    for (int b = 0; b < 8; ++b) {
      const float* xb = x + (long long)b*64*HW;
      float* ob = out + (long long)b*64*HW;
      k1_mfma <<<1024, 256, 0, stream>>>(xb, wg, wqkv, A);
      k2a_dw  <<<512,  256, 0, stream>>>(A, wgd, wqd, Vv, GG);
      k2b_qk  <<<8*NBAND, 64, 0, stream>>>(A, wqd, GRP);
      k2c_attn<<<8,    64,  0, stream>>>(GRP, tp, ATT);
      k3_out  <<<256,  256, 0, stream>>>(Vv, GG, ATT, wpj, ob);
    }
  } else {
    k_signal<<<2048,256,0,stream>>>(out, (long long)out_size, 1000.0f);
  }
}

// Round 11
// 431.908 us; speedup vs baseline: 3.3067x; 1.0658x over previous
//
#include <hip/hip_runtime.h>

typedef _Float16 f16;
using f16x4 = __attribute__((ext_vector_type(4))) _Float16;
using f16x8 = __attribute__((ext_vector_type(8))) _Float16;
using f32x4 = __attribute__((ext_vector_type(4))) float;

#define HW 65536
#define NBAND 16
#define ROWS 16
#define RS 320   // k2b ring row stride in f16

// own erf (A&S 7.1.26, |err| <= 1.5e-7); __expf is HW v_exp_f32
static __device__ __forceinline__ float my_erf(float v) {
  float x = fabsf(v);
  float t = 1.f / (1.f + 0.3275911f * x);
  float y = t * (0.254829592f + t * (-0.284496736f + t * (1.421413741f
          + t * (-1.453152027f + t * 1.061405429f))));
  float r = 1.f - y * __expf(-x * x);
  return v < 0.f ? -r : r;
}
static __device__ __forceinline__ float my_gelu(float s) {
  return 0.5f * s * (1.f + my_erf(s * 0.70710678118654752f));
}

__global__ void TRA_Attention_15281493639325_kernel() {}

__global__ void k_signal(float* out, long long n, float val) {
  long long i = (long long)blockIdx.x * blockDim.x + threadIdx.x;
  long long stride = (long long)gridDim.x * blockDim.x;
  for (; i < n; i += stride) out[i] = val;
}

// ---------------------------------------------------------------------------
// K1 (MFMA f16): fused 1x1 conv, 256 out ch. Tile M=256 x N=64 pos, K=64.
// grid = nb*1024. LDS 40KB, XOR-swizzled 16B chunks.
// Epilogue: acc -> LDS f16 [256][72] -> coalesced f16x8 global stores.
// ---------------------------------------------------------------------------
__global__ __launch_bounds__(256) void k1_mfma(
    const float* __restrict__ x, const float* __restrict__ w_gate,
    const float* __restrict__ w_qkv, f16* __restrict__ A)
{
  __shared__ __align__(16) unsigned char lds[256*128 + 64*128];
  unsigned char* wl = lds;
  unsigned char* xs = lds + 256*128;

  const int tid = threadIdx.x, blk = blockIdx.x;
  const int b = blk >> 10;
  const long long p0 = (long long)(blk & 1023) * 64;

  for (int cid = tid; cid < 4096; cid += 256) {
    int m = cid >> 4, kc = cid & 15;
    const float* src = (m < 64) ? (w_gate + m*64 + kc*4)
                                : (w_qkv + (m-64)*64 + kc*4);
    float4 f = *(const float4*)src;
    int hm = ((m & 7) ^ ((m >> 3) & 7)) << 4;
    f16x4 pk = { (f16)f.x, (f16)f.y, (f16)f.z, (f16)f.w };
    *(f16x4*)(wl + m*128 + ((kc*8) ^ hm)) = pk;
  }
  for (int cid = tid; cid < 1024; cid += 256) {
    int k = cid >> 4, c = cid & 15;
    float4 f = *(const float4*)(x + ((long long)b*64 + k)*HW + p0 + c*4);
    const float* e = (const float*)&f;
    #pragma unroll
    for (int i = 0; i < 4; ++i) {
      int p = c*4 + i;
      int hp = ((p & 7) ^ ((p >> 3) & 7)) << 4;
      *(f16*)(xs + p*128 + ((2*k) ^ hp)) = (f16)e[i];
    }
  }
  __syncthreads();

  const int wave = tid >> 6, lane = tid & 63;
  const int m0 = (wave >> 1) * 128, n0 = (wave & 1) * 32;
  const int lr = lane & 15, lg = lane >> 4;

  f32x4 acc[8][2];
  #pragma unroll
  for (int i = 0; i < 8; ++i)
    #pragma unroll
    for (int j = 0; j < 2; ++j) acc[i][j] = (f32x4){0.f,0.f,0.f,0.f};

  #pragma unroll
  for (int ks = 0; ks < 2; ++ks) {
    f16x8 af[8], bfr[2];
    #pragma unroll
    for (int mi = 0; mi < 8; ++mi) {
      int m = m0 + mi*16 + lr;
      int hm = ((m & 7) ^ ((m >> 3) & 7)) << 4;
      af[mi] = *(const f16x8*)(wl + m*128 + ((ks*64 + lg*16) ^ hm));
    }
    #pragma unroll
    for (int ni = 0; ni < 2; ++ni) {
      int p = n0 + ni*16 + lr;
      int hp = ((p & 7) ^ ((p >> 3) & 7)) << 4;
      bfr[ni] = *(const f16x8*)(xs + p*128 + ((ks*64 + lg*16) ^ hp));
    }
    #pragma unroll
    for (int mi = 0; mi < 8; ++mi)
      #pragma unroll
      for (int ni = 0; ni < 2; ++ni)
        acc[mi][ni] = __builtin_amdgcn_mfma_f32_16x16x32_f16(
            af[mi], bfr[ni], acc[mi][ni], 0, 0, 0);
  }

  // all operand ds_reads are complete (lgkmcnt before MFMA); barrier, then
  // reuse LDS as f16 out-tile [256 ch][72] (144B row stride, 16B aligned).
  __syncthreads();
  f16* os = (f16*)lds;
  #pragma unroll
  for (int mi = 0; mi < 8; ++mi)
    #pragma unroll
    for (int ni = 0; ni < 2; ++ni)
      #pragma unroll
      for (int r = 0; r < 4; ++r) {
        int m = m0 + mi*16 + lg*4 + r;
        int p = n0 + ni*16 + lr;
        os[m*72 + p] = (f16)acc[mi][ni][r];
      }
  __syncthreads();

  // coalesced stores: 8 passes x 256 thr x f16x8; 8 threads cover one row.
  #pragma unroll
  for (int pass = 0; pass < 8; ++pass) {
    int idx = pass*256 + tid;
    int row = idx >> 3, c8 = idx & 7;
    f16x8 v = *(const f16x8*)(os + row*72 + c8*8);
    *(f16x8*)(A + ((long long)b*256 + row)*HW + p0 + c8*8) = v;
  }
}

// ---------------------------------------------------------------------------
// K2a (reg-rolling, LDS-free): depthwise 3x3 for gate (+GELU) and v channels.
// ---------------------------------------------------------------------------
__global__ __launch_bounds__(256) void k2a_dw(
    const f16* __restrict__ A, const float* __restrict__ w_gate_dw,
    const float* __restrict__ w_qkv_dw, f16* __restrict__ Vv, f16* __restrict__ GG)
{
  const int tid = threadIdx.x, blk = blockIdx.x;
  const int yband = blk & 3, ch2 = (blk >> 2) & 127, b = blk >> 9;
  const bool isv = ch2 >= 64;
  const int c = isv ? ch2 - 64 : ch2;
  const f16* src = A + ((long long)b*256 + (isv ? 192 + c : c)) * HW;
  const float* wsrc = isv ? (w_qkv_dw + (128 + c)*9) : (w_gate_dw + c*9);
  f16* dst = (isv ? Vv : GG) + ((long long)b*64 + c) * HW;

  float wd[9];
  #pragma unroll
  for (int j = 0; j < 9; ++j) wd[j] = wsrc[j];

  const int xc = tid & 31, ysub = tid >> 5;
  const int lane = tid & 63;
  const int xbase = xc * 8;
  const int y0 = yband * 64 + ysub * 8;

  float rb[3][10];

  auto load_row = [&](int y, float* r) {
    if (y >= 0 && y < 256) {
      uint4 raw = *(const uint4*)(src + y*256 + xbase);
      const f16* e = (const f16*)&raw;
      #pragma unroll
      for (int t = 0; t < 8; ++t) r[1 + t] = (float)e[t];
    } else {
      #pragma unroll
      for (int t = 0; t < 8; ++t) r[1 + t] = 0.f;
    }
    float lf = __shfl(r[8], lane - 1);
    float rf = __shfl(r[1], lane + 1);
    r[0] = (xc == 0)  ? 0.f : lf;
    r[9] = (xc == 31) ? 0.f : rf;
  };

  load_row(y0 - 1, rb[0]);
  load_row(y0,     rb[1]);

  #pragma unroll
  for (int i = 0; i < 8; ++i) {
    load_row(y0 + i + 1, rb[(i + 2) % 3]);
    const float* rm = rb[i % 3];
    const float* r0 = rb[(i + 1) % 3];
    const float* rp = rb[(i + 2) % 3];
    f16x8 st;
    #pragma unroll
    for (int j = 0; j < 8; ++j) {
      float s = wd[0]*rm[j] + wd[1]*rm[j+1] + wd[2]*rm[j+2]
              + wd[3]*r0[j] + wd[4]*r0[j+1] + wd[5]*r0[j+2]
              + wd[6]*rp[j] + wd[7]*rp[j+1] + wd[8]*rp[j+2];
      if (!isv) s = my_gelu(s);
      st[j] = (f16)s;
    }
    *(f16x8*)(dst + (y0 + i)*256 + xbase) = st;
  }
}

// ---------------------------------------------------------------------------
// K2b (MFMA gram): dwconv for q,k of one head fused with 16x16 gram via
// mfma_f32_16x16x32_f16 with identical A/B fragments. 1 wave per
// (b,h,16-row band). GRP layout: [b][h][band][80] = qq[8], kk[8], qk[64].
// ---------------------------------------------------------------------------
__device__ __forceinline__ int ridx(int c, int slot, int i) {
  return ((((c << 2) | slot) * RS) + i) ^ ((c & 7) << 3);
}

__global__ __launch_bounds__(64) void k2b_qk(
    const f16* __restrict__ A, const float* __restrict__ w_qkv_dw,
    float* __restrict__ GRP)
{
  __shared__ __align__(16) f16 ring[16*4*RS];
  const int lane = threadIdx.x, blk = blockIdx.x;
  const int band = blk & (NBAND-1), h = (blk >> 4) & 7, b = blk >> 7;

  const int c  = lane & 15, g  = lane >> 4;
  const int cs = lane >> 2, q4 = lane & 3;

  const int wrow = (c < 8) ? (h*8 + c) : (64 + h*8 + (c - 8));
  float wq[9];
  #pragma unroll
  for (int j = 0; j < 9; ++j) wq[j] = w_qkv_dw[wrow*9 + j];

  const f16* sbase = A + ((long long)b*256 +
      (cs < 8 ? 64 + h*8 + cs : 128 + h*8 + (cs - 8))) * HW;

  ring[ridx(cs, q4, 7)]   = (f16)0.f;
  ring[ridx(cs, q4, 264)] = (f16)0.f;

  auto load_row = [&](int yy, uint4* r) {
    if (yy >= 0 && yy < 256) {
      const f16* p = sbase + yy*256 + q4*64;
      #pragma unroll
      for (int t = 0; t < 8; ++t) r[t] = *(const uint4*)(p + t*8);
    } else {
      #pragma unroll
      for (int t = 0; t < 8; ++t) r[t] = make_uint4(0u,0u,0u,0u);
    }
  };
  auto write_row = [&](int slot, const uint4* r) {
    #pragma unroll
    for (int t = 0; t < 8; ++t)
      *(uint4*)&ring[ridx(cs, slot, 8 + q4*64 + t*8)] = r[t];
  };

  const int y0 = band * ROWS;
  {
    uint4 r[8];
    load_row(y0-1, r); write_row((y0+3)&3, r);
    load_row(y0,   r); write_row((y0+4)&3, r);
    load_row(y0+1, r); write_row((y0+5)&3, r);
  }
  __syncthreads();

  f32x4 acc = (f32x4){0.f, 0.f, 0.f, 0.f};

  for (int y = y0; y < y0 + ROWS; ++y) {
    uint4 r[8];
    const bool pf = (y + 2 <= y0 + ROWS);
    if (pf) load_row(y + 2, r);

    const int s0 = (y+3)&3, s1 = (y+4)&3, s2 = (y+5)&3;
    #pragma unroll
    for (int q = 0; q < 8; ++q) {
      const int base = 7 + q*32 + g*8;
      float v0[10], v1[10], v2[10];
      #pragma unroll
      for (int t = 0; t < 10; ++t) {
        v0[t] = (float)ring[ridx(c, s0, base+t)];
        v1[t] = (float)ring[ridx(c, s1, base+t)];
        v2[t] = (float)ring[ridx(c, s2, base+t)];
      }
      f16x8 frag;
      #pragma unroll
      for (int j = 0; j < 8; ++j) {
        float s = wq[0]*v0[j] + wq[1]*v0[j+1] + wq[2]*v0[j+2]
                + wq[3]*v1[j] + wq[4]*v1[j+1] + wq[5]*v1[j+2]
                + wq[6]*v2[j] + wq[7]*v2[j+1] + wq[8]*v2[j+2];
        frag[j] = (f16)s;
      }
      acc = __builtin_amdgcn_mfma_f32_16x16x32_f16(frag, frag, acc, 0, 0, 0);
    }
    if (pf) write_row((y+6)&3, r);
    __syncthreads();
  }

  const long long gbase = (long long)((b*8 + h)*NBAND + band) * 80;
  #pragma unroll
  for (int reg = 0; reg < 4; ++reg) {
    int rrow = g*4 + reg;
    float val = acc[reg];
    if (rrow == c) GRP[gbase + c] = val;
    else if (rrow < 8 && c >= 8) GRP[gbase + 16 + rrow*8 + (c-8)] = val;
  }
}

// ---------------------------------------------------------------------------
// K2c: reduce band partials, normalize, temperature, softmax. grid = nb*8
// ---------------------------------------------------------------------------
__global__ __launch_bounds__(64) void k2c_attn(
    const float* __restrict__ GRP, const float* __restrict__ temp,
    float* __restrict__ ATT)
{
  __shared__ float s[80];
  const int tid = threadIdx.x;
  const int h = blockIdx.x & 7, b = blockIdx.x >> 3;
  for (int i = tid; i < 80; i += 64) {
    float v = 0.f;
    for (int band = 0; band < NBAND; ++band)
      v += GRP[(((b*8 + h)*NBAND + band) * 80) + i];
    s[i] = v;
  }
  __syncthreads();
  const int c = tid >> 3, d = tid & 7;
  float nq = fmaxf(sqrtf(s[c]), 1e-12f);
  float nk = fmaxf(sqrtf(s[8 + d]), 1e-12f);
  float logit = s[16 + c*8 + d] / (nq * nk) * temp[h];
  float m = logit;
  #pragma unroll
  for (int off = 4; off; off >>= 1) m = fmaxf(m, __shfl_xor(m, off));
  float e = __expf(logit - m);
  float sum = e;
  #pragma unroll
  for (int off = 4; off; off >>= 1) sum += __shfl_xor(sum, off);
  ATT[((b*8 + h)*8 + c)*8 + d] = e / sum;
}

// ---------------------------------------------------------------------------
// K3: out = conv1x1( gelu(gate) * (attn @ v), w_proj ). grid = nb*256. f32 out.
// ---------------------------------------------------------------------------
__global__ __launch_bounds__(256) void k3_out(
    const f16* __restrict__ Vv, const f16* __restrict__ GG,
    const float* __restrict__ ATT, const float* __restrict__ w_proj,
    float* __restrict__ out)
{
  __shared__ float attn_s[512];
  __shared__ float wp[4096];
  const int tid = threadIdx.x;
  const int y = blockIdx.x & 255, b = blockIdx.x >> 8;
  for (int i = tid; i < 512; i += 256) attn_s[i] = ATT[b*512 + i];
  for (int i = tid; i < 4096; i += 256) wp[i] = w_proj[i];
  __syncthreads();

  const int xx = tid;
  const long long pos = (long long)y*256 + xx;
  float g[64];
  #pragma unroll
  for (int hd = 0; hd < 8; ++hd) {
    float vv[8];
    #pragma unroll
    for (int d = 0; d < 8; ++d)
      vv[d] = (float)Vv[((long long)b*64 + hd*8 + d)*HW + pos];
    #pragma unroll
    for (int c = 0; c < 8; ++c) {
      float av = 0.f;
      #pragma unroll
      for (int d = 0; d < 8; ++d)
        av += attn_s[hd*64 + c*8 + d] * vv[d];
      float gg = (float)GG[((long long)b*64 + hd*8 + c)*HW + pos];
      g[hd*8 + c] = gg * av;
    }
  }
  for (int co = 0; co < 64; ++co) {
    float acc = 0.f;
    const float4* wr = (const float4*)(wp + co*64);
    #pragma unroll
    for (int q4 = 0; q4 < 16; ++q4) {
      float4 wv = wr[q4];
      acc += wv.x * g[q4*4 + 0] + wv.y * g[q4*4 + 1]
           + wv.z * g[q4*4 + 2] + wv.w * g[q4*4 + 3];
    }
    out[((long long)b*64 + co)*HW + pos] = acc;
  }
}

// ---------------------------------------------------------------------------
extern "C" void kernel_launch(void* const* d_in, const int* in_sizes, int n_in,
                              void* d_out, int out_size, void* d_ws, size_t ws_size,
                              hipStream_t stream)
{
  float* out = (float*)d_out;

  int mp[7] = {-1,-1,-1,-1,-1,-1,-1};
  bool ok = (n_in == 7);
  if (ok) {
    int n4 = 0;
    for (int i = 0; i < 7; ++i) {
      long s = in_sizes[i];
      if      (s == 33554432) mp[0] = i;            // x
      else if (s == 576)      mp[2] = i;            // w_gate_dw
      else if (s == 12288)    mp[3] = i;            // w_qkv
      else if (s == 1728)     mp[4] = i;            // w_qkv_dw
      else if (s == 8)        mp[6] = i;            // temperature
      else if (s == 4096)     { if (n4 == 0) mp[1] = i; else mp[5] = i; ++n4; }
    }
    ok = ok && (n4 == 2);
    for (int i = 0; i < 7; ++i) ok = ok && (mp[i] >= 0);
  }
  if (!ok) { k_signal<<<2048,256,0,stream>>>(out, (long long)out_size, 2000.0f); return; }
  if (out_size != 33554432) { k_signal<<<2048,256,0,stream>>>(out, (long long)out_size, 3000.0f); return; }

  const float* x    = (const float*)d_in[mp[0]];
  const float* wg   = (const float*)d_in[mp[1]];
  const float* wgd  = (const float*)d_in[mp[2]];
  const float* wqkv = (const float*)d_in[mp[3]];
  const float* wqd  = (const float*)d_in[mp[4]];
  const float* wpj  = (const float*)d_in[mp[5]];
  const float* tp   = (const float*)d_in[mp[6]];

  unsigned char* ws = (unsigned char*)d_ws;
  const size_t GRP_SZ   = 8UL*8*NBAND*80*4;
  const size_t FULL     = 402653184UL + GRP_SZ + 16384UL;
  const size_t PERB_GRP = 8UL*NBAND*80*4;
  const size_t PERB     = 50331648UL + PERB_GRP + 2048UL;

  if (ws != nullptr && ws_size >= FULL) {
    f16*   A    = (f16*)ws;
    f16*   Vv   = (f16*)(ws + 268435456UL);
    f16*   GG   = (f16*)(ws + 335544320UL);
    float* GRP  = (float*)(ws + 402653184UL);
    float* ATT  = (float*)(ws + 402653184UL + GRP_SZ);
    k1_mfma <<<8192, 256, 0, stream>>>(x, wg, wqkv, A);
    k2a_dw  <<<4096, 256, 0, stream>>>(A, wgd, wqd, Vv, GG);
    k2b_qk  <<<8*8*NBAND, 64, 0, stream>>>(A, wqd, GRP);
    k2c_attn<<<64,   64,  0, stream>>>(GRP, tp, ATT);
    k3_out  <<<2048, 256, 0, stream>>>(Vv, GG, ATT, wpj, out);
  } else if (ws != nullptr && ws_size >= PERB) {
    f16*   A    = (f16*)ws;
    f16*   Vv   = (f16*)(ws + 33554432UL);
    f16*   GG   = (f16*)(ws + 41943040UL);
    float* GRP  = (float*)(ws + 50331648UL);
    float* ATT  = (float*)(ws + 50331648UL + PERB_GRP);
    for (int b = 0; b < 8; ++b) {
      const float* xb = x + (long long)b*64*HW;
      float* ob = out + (long long)b*64*HW;
      k1_mfma <<<1024, 256, 0, stream>>>(xb, wg, wqkv, A);
      k2a_dw  <<<512,  256, 0, stream>>>(A, wgd, wqd, Vv, GG);
      k2b_qk  <<<8*NBAND, 64, 0, stream>>>(A, wqd, GRP);
      k2c_attn<<<8,    64,  0, stream>>>(GRP, tp, ATT);
      k3_out  <<<256,  256, 0, stream>>>(Vv, GG, ATT, wpj, ob);
    }
  } else {
    k_signal<<<2048,256,0,stream>>>(out, (long long)out_size, 1000.0f);
  }
}

// Round 12
// 354.370 us; speedup vs baseline: 4.0302x; 1.2188x over previous
//
#include <hip/hip_runtime.h>

typedef _Float16 f16;
using f16x4 = __attribute__((ext_vector_type(4))) _Float16;
using f16x8 = __attribute__((ext_vector_type(8))) _Float16;
using f32x4 = __attribute__((ext_vector_type(4))) float;

#define HW 65536
#define NBAND 16
#define ROWS 16
#define RS 320   // k2b ring row stride in f16

// own erf (A&S 7.1.26, |err| <= 1.5e-7); __expf is HW v_exp_f32
static __device__ __forceinline__ float my_erf(float v) {
  float x = fabsf(v);
  float t = 1.f / (1.f + 0.3275911f * x);
  float y = t * (0.254829592f + t * (-0.284496736f + t * (1.421413741f
          + t * (-1.453152027f + t * 1.061405429f))));
  float r = 1.f - y * __expf(-x * x);
  return v < 0.f ? -r : r;
}
static __device__ __forceinline__ float my_gelu(float s) {
  return 0.5f * s * (1.f + my_erf(s * 0.70710678118654752f));
}

__global__ void TRA_Attention_15281493639325_kernel() {}

__global__ void k_signal(float* out, long long n, float val) {
  long long i = (long long)blockIdx.x * blockDim.x + threadIdx.x;
  long long stride = (long long)gridDim.x * blockDim.x;
  for (; i < n; i += stride) out[i] = val;
}

// ---------------------------------------------------------------------------
// K1 (MFMA f16): fused 1x1 conv, 256 out ch. Tile M=256 x N=64 pos, K=64.
// grid = nb*1024. LDS 40KB, XOR-swizzled 16B chunks.
// Epilogue: acc -> LDS f16 [256][72] -> coalesced f16x8 global stores.
// ---------------------------------------------------------------------------
__global__ __launch_bounds__(256) void k1_mfma(
    const float* __restrict__ x, const float* __restrict__ w_gate,
    const float* __restrict__ w_qkv, f16* __restrict__ A)
{
  __shared__ __align__(16) unsigned char lds[256*128 + 64*128];
  unsigned char* wl = lds;
  unsigned char* xs = lds + 256*128;

  const int tid = threadIdx.x, blk = blockIdx.x;
  const int b = blk >> 10;
  const long long p0 = (long long)(blk & 1023) * 64;

  for (int cid = tid; cid < 4096; cid += 256) {
    int m = cid >> 4, kc = cid & 15;
    const float* src = (m < 64) ? (w_gate + m*64 + kc*4)
                                : (w_qkv + (m-64)*64 + kc*4);
    float4 f = *(const float4*)src;
    int hm = ((m & 7) ^ ((m >> 3) & 7)) << 4;
    f16x4 pk = { (f16)f.x, (f16)f.y, (f16)f.z, (f16)f.w };
    *(f16x4*)(wl + m*128 + ((kc*8) ^ hm)) = pk;
  }
  for (int cid = tid; cid < 1024; cid += 256) {
    int k = cid >> 4, c = cid & 15;
    float4 f = *(const float4*)(x + ((long long)b*64 + k)*HW + p0 + c*4);
    const float* e = (const float*)&f;
    #pragma unroll
    for (int i = 0; i < 4; ++i) {
      int p = c*4 + i;
      int hp = ((p & 7) ^ ((p >> 3) & 7)) << 4;
      *(f16*)(xs + p*128 + ((2*k) ^ hp)) = (f16)e[i];
    }
  }
  __syncthreads();

  const int wave = tid >> 6, lane = tid & 63;
  const int m0 = (wave >> 1) * 128, n0 = (wave & 1) * 32;
  const int lr = lane & 15, lg = lane >> 4;

  f32x4 acc[8][2];
  #pragma unroll
  for (int i = 0; i < 8; ++i)
    #pragma unroll
    for (int j = 0; j < 2; ++j) acc[i][j] = (f32x4){0.f,0.f,0.f,0.f};

  #pragma unroll
  for (int ks = 0; ks < 2; ++ks) {
    f16x8 af[8], bfr[2];
    #pragma unroll
    for (int mi = 0; mi < 8; ++mi) {
      int m = m0 + mi*16 + lr;
      int hm = ((m & 7) ^ ((m >> 3) & 7)) << 4;
      af[mi] = *(const f16x8*)(wl + m*128 + ((ks*64 + lg*16) ^ hm));
    }
    #pragma unroll
    for (int ni = 0; ni < 2; ++ni) {
      int p = n0 + ni*16 + lr;
      int hp = ((p & 7) ^ ((p >> 3) & 7)) << 4;
      bfr[ni] = *(const f16x8*)(xs + p*128 + ((ks*64 + lg*16) ^ hp));
    }
    #pragma unroll
    for (int mi = 0; mi < 8; ++mi)
      #pragma unroll
      for (int ni = 0; ni < 2; ++ni)
        acc[mi][ni] = __builtin_amdgcn_mfma_f32_16x16x32_f16(
            af[mi], bfr[ni], acc[mi][ni], 0, 0, 0);
  }

  __syncthreads();
  f16* os = (f16*)lds;
  #pragma unroll
  for (int mi = 0; mi < 8; ++mi)
    #pragma unroll
    for (int ni = 0; ni < 2; ++ni)
      #pragma unroll
      for (int r = 0; r < 4; ++r) {
        int m = m0 + mi*16 + lg*4 + r;
        int p = n0 + ni*16 + lr;
        os[m*72 + p] = (f16)acc[mi][ni][r];
      }
  __syncthreads();

  #pragma unroll
  for (int pass = 0; pass < 8; ++pass) {
    int idx = pass*256 + tid;
    int row = idx >> 3, c8 = idx & 7;
    f16x8 v = *(const f16x8*)(os + row*72 + c8*8);
    *(f16x8*)(A + ((long long)b*256 + row)*HW + p0 + c8*8) = v;
  }
}

// ---------------------------------------------------------------------------
// K2a (reg-rolling, LDS-free): depthwise 3x3 for gate (+GELU) and v channels.
// ---------------------------------------------------------------------------
__global__ __launch_bounds__(256) void k2a_dw(
    const f16* __restrict__ A, const float* __restrict__ w_gate_dw,
    const float* __restrict__ w_qkv_dw, f16* __restrict__ Vv, f16* __restrict__ GG)
{
  const int tid = threadIdx.x, blk = blockIdx.x;
  const int yband = blk & 3, ch2 = (blk >> 2) & 127, b = blk >> 9;
  const bool isv = ch2 >= 64;
  const int c = isv ? ch2 - 64 : ch2;
  const f16* src = A + ((long long)b*256 + (isv ? 192 + c : c)) * HW;
  const float* wsrc = isv ? (w_qkv_dw + (128 + c)*9) : (w_gate_dw + c*9);
  f16* dst = (isv ? Vv : GG) + ((long long)b*64 + c) * HW;

  float wd[9];
  #pragma unroll
  for (int j = 0; j < 9; ++j) wd[j] = wsrc[j];

  const int xc = tid & 31, ysub = tid >> 5;
  const int lane = tid & 63;
  const int xbase = xc * 8;
  const int y0 = yband * 64 + ysub * 8;

  float rb[3][10];

  auto load_row = [&](int y, float* r) {
    if (y >= 0 && y < 256) {
      uint4 raw = *(const uint4*)(src + y*256 + xbase);
      const f16* e = (const f16*)&raw;
      #pragma unroll
      for (int t = 0; t < 8; ++t) r[1 + t] = (float)e[t];
    } else {
      #pragma unroll
      for (int t = 0; t < 8; ++t) r[1 + t] = 0.f;
    }
    float lf = __shfl(r[8], lane - 1);
    float rf = __shfl(r[1], lane + 1);
    r[0] = (xc == 0)  ? 0.f : lf;
    r[9] = (xc == 31) ? 0.f : rf;
  };

  load_row(y0 - 1, rb[0]);
  load_row(y0,     rb[1]);

  #pragma unroll
  for (int i = 0; i < 8; ++i) {
    load_row(y0 + i + 1, rb[(i + 2) % 3]);
    const float* rm = rb[i % 3];
    const float* r0 = rb[(i + 1) % 3];
    const float* rp = rb[(i + 2) % 3];
    f16x8 st;
    #pragma unroll
    for (int j = 0; j < 8; ++j) {
      float s = wd[0]*rm[j] + wd[1]*rm[j+1] + wd[2]*rm[j+2]
              + wd[3]*r0[j] + wd[4]*r0[j+1] + wd[5]*r0[j+2]
              + wd[6]*rp[j] + wd[7]*rp[j+1] + wd[8]*rp[j+2];
      if (!isv) s = my_gelu(s);
      st[j] = (f16)s;
    }
    *(f16x8*)(dst + (y0 + i)*256 + xbase) = st;
  }
}

// ---------------------------------------------------------------------------
// K2b (MFMA gram): dwconv for q,k of one head fused with 16x16 gram via
// mfma_f32_16x16x32_f16 with identical A/B fragments. 1 wave per
// (b,h,16-row band). GRP layout: [b][h][band][80] = qq[8], kk[8], qk[64].
// ---------------------------------------------------------------------------
__device__ __forceinline__ int ridx(int c, int slot, int i) {
  return ((((c << 2) | slot) * RS) + i) ^ ((c & 7) << 3);
}

__global__ __launch_bounds__(64) void k2b_qk(
    const f16* __restrict__ A, const float* __restrict__ w_qkv_dw,
    float* __restrict__ GRP)
{
  __shared__ __align__(16) f16 ring[16*4*RS];
  const int lane = threadIdx.x, blk = blockIdx.x;
  const int band = blk & (NBAND-1), h = (blk >> 4) & 7, b = blk >> 7;

  const int c  = lane & 15, g  = lane >> 4;
  const int cs = lane >> 2, q4 = lane & 3;

  const int wrow = (c < 8) ? (h*8 + c) : (64 + h*8 + (c - 8));
  float wq[9];
  #pragma unroll
  for (int j = 0; j < 9; ++j) wq[j] = w_qkv_dw[wrow*9 + j];

  const f16* sbase = A + ((long long)b*256 +
      (cs < 8 ? 64 + h*8 + cs : 128 + h*8 + (cs - 8))) * HW;

  ring[ridx(cs, q4, 7)]   = (f16)0.f;
  ring[ridx(cs, q4, 264)] = (f16)0.f;

  auto load_row = [&](int yy, uint4* r) {
    if (yy >= 0 && yy < 256) {
      const f16* p = sbase + yy*256 + q4*64;
      #pragma unroll
      for (int t = 0; t < 8; ++t) r[t] = *(const uint4*)(p + t*8);
    } else {
      #pragma unroll
      for (int t = 0; t < 8; ++t) r[t] = make_uint4(0u,0u,0u,0u);
    }
  };
  auto write_row = [&](int slot, const uint4* r) {
    #pragma unroll
    for (int t = 0; t < 8; ++t)
      *(uint4*)&ring[ridx(cs, slot, 8 + q4*64 + t*8)] = r[t];
  };

  const int y0 = band * ROWS;
  {
    uint4 r[8];
    load_row(y0-1, r); write_row((y0+3)&3, r);
    load_row(y0,   r); write_row((y0+4)&3, r);
    load_row(y0+1, r); write_row((y0+5)&3, r);
  }
  __syncthreads();

  f32x4 acc = (f32x4){0.f, 0.f, 0.f, 0.f};

  for (int y = y0; y < y0 + ROWS; ++y) {
    uint4 r[8];
    const bool pf = (y + 2 <= y0 + ROWS);
    if (pf) load_row(y + 2, r);

    const int s0 = (y+3)&3, s1 = (y+4)&3, s2 = (y+5)&3;
    #pragma unroll
    for (int q = 0; q < 8; ++q) {
      const int base = 7 + q*32 + g*8;
      float v0[10], v1[10], v2[10];
      #pragma unroll
      for (int t = 0; t < 10; ++t) {
        v0[t] = (float)ring[ridx(c, s0, base+t)];
        v1[t] = (float)ring[ridx(c, s1, base+t)];
        v2[t] = (float)ring[ridx(c, s2, base+t)];
      }
      f16x8 frag;
      #pragma unroll
      for (int j = 0; j < 8; ++j) {
        float s = wq[0]*v0[j] + wq[1]*v0[j+1] + wq[2]*v0[j+2]
                + wq[3]*v1[j] + wq[4]*v1[j+1] + wq[5]*v1[j+2]
                + wq[6]*v2[j] + wq[7]*v2[j+1] + wq[8]*v2[j+2];
        frag[j] = (f16)s;
      }
      acc = __builtin_amdgcn_mfma_f32_16x16x32_f16(frag, frag, acc, 0, 0, 0);
    }
    if (pf) write_row((y+6)&3, r);
    __syncthreads();
  }

  const long long gbase = (long long)((b*8 + h)*NBAND + band) * 80;
  #pragma unroll
  for (int reg = 0; reg < 4; ++reg) {
    int rrow = g*4 + reg;
    float val = acc[reg];
    if (rrow == c) GRP[gbase + c] = val;
    else if (rrow < 8 && c >= 8) GRP[gbase + 16 + rrow*8 + (c-8)] = val;
  }
}

// ---------------------------------------------------------------------------
// K2c: reduce band partials, normalize, temperature, softmax. grid = nb*8
// ---------------------------------------------------------------------------
__global__ __launch_bounds__(64) void k2c_attn(
    const float* __restrict__ GRP, const float* __restrict__ temp,
    float* __restrict__ ATT)
{
  __shared__ float s[80];
  const int tid = threadIdx.x;
  const int h = blockIdx.x & 7, b = blockIdx.x >> 3;
  for (int i = tid; i < 80; i += 64) {
    float v = 0.f;
    for (int band = 0; band < NBAND; ++band)
      v += GRP[(((b*8 + h)*NBAND + band) * 80) + i];
    s[i] = v;
  }
  __syncthreads();
  const int c = tid >> 3, d = tid & 7;
  float nq = fmaxf(sqrtf(s[c]), 1e-12f);
  float nk = fmaxf(sqrtf(s[8 + d]), 1e-12f);
  float logit = s[16 + c*8 + d] / (nq * nk) * temp[h];
  float m = logit;
  #pragma unroll
  for (int off = 4; off; off >>= 1) m = fmaxf(m, __shfl_xor(m, off));
  float e = __expf(logit - m);
  float sum = e;
  #pragma unroll
  for (int off = 4; off; off >>= 1) sum += __shfl_xor(sum, off);
  ATT[((b*8 + h)*8 + c)*8 + d] = e / sum;
}

// ---------------------------------------------------------------------------
// K3 (MFMA proj): g = gelu(gate)*(attn@v) -> f16 LDS tile -> MFMA with
// w_proj (f16) -> f32 out. Block = 256 thr, one image row (256 pos).
// grid = nb*256.
// ---------------------------------------------------------------------------
__global__ __launch_bounds__(256) void k3_out(
    const f16* __restrict__ Vv, const f16* __restrict__ GG,
    const float* __restrict__ ATT, const float* __restrict__ w_proj,
    float* __restrict__ out)
{
  __shared__ __align__(16) unsigned char lds[64*128 + 256*128 + 2048];
  unsigned char* wl = lds;                    // wp f16 [64co][64ch] swz rows
  unsigned char* xs = lds + 64*128;           // g  f16 [256pos][64ch] swz rows
  float* attn_s = (float*)(lds + 64*128 + 256*128);

  const int tid = threadIdx.x;
  const int y = blockIdx.x & 255, b = blockIdx.x >> 8;

  // stage wp (f32 -> f16, swizzled) + attn
  for (int cid = tid; cid < 1024; cid += 256) {
    int m = cid >> 4, kc = cid & 15;
    float4 f = *(const float4*)(w_proj + m*64 + kc*4);
    int hm = ((m & 7) ^ ((m >> 3) & 7)) << 4;
    f16x4 pk = { (f16)f.x, (f16)f.y, (f16)f.z, (f16)f.w };
    *(f16x4*)(wl + m*128 + ((kc*8) ^ hm)) = pk;
  }
  for (int i = tid; i < 512; i += 256) attn_s[i] = ATT[b*512 + i];
  __syncthreads();

  // gating: thread = (pos-group pg=tid&31, head hd=tid>>5); 32 lanes of a
  // half-wave read contiguous 512B per d-load.
  {
    const int pg = tid & 31, hd = tid >> 5;
    const long long base = ((long long)b*64 + hd*8)*HW + (long long)y*256 + pg*8;
    f16x8 vv[8], gg[8];
    #pragma unroll
    for (int d = 0; d < 8; ++d)
      vv[d] = *(const f16x8*)(Vv + base + (long long)d*HW);
    #pragma unroll
    for (int c = 0; c < 8; ++c)
      gg[c] = *(const f16x8*)(GG + base + (long long)c*HW);
    float a[8][8];
    #pragma unroll
    for (int c = 0; c < 8; ++c)
      #pragma unroll
      for (int d = 0; d < 8; ++d) a[c][d] = attn_s[hd*64 + c*8 + d];
    #pragma unroll
    for (int j = 0; j < 8; ++j) {
      int p = pg*8 + j;
      int hp = ((p & 7) ^ ((p >> 3) & 7)) << 4;
      f16x8 st;
      #pragma unroll
      for (int c = 0; c < 8; ++c) {
        float av = 0.f;
        #pragma unroll
        for (int d = 0; d < 8; ++d) av += a[c][d] * (float)vv[d][j];
        st[c] = (f16)((float)gg[c][j] * av);
      }
      *(f16x8*)(xs + p*128 + ((hd*16) ^ hp)) = st;
    }
  }
  __syncthreads();

  // MFMA proj: wave w handles pos strip n0=w*64; M=64, N=64, K=64.
  const int wave = tid >> 6, lane = tid & 63;
  const int n0 = wave * 64;
  const int lr = lane & 15, lg = lane >> 4;

  f32x4 acc[4][4];
  #pragma unroll
  for (int i = 0; i < 4; ++i)
    #pragma unroll
    for (int j = 0; j < 4; ++j) acc[i][j] = (f32x4){0.f,0.f,0.f,0.f};

  #pragma unroll
  for (int ks = 0; ks < 2; ++ks) {
    f16x8 af[4], bfr[4];
    #pragma unroll
    for (int mi = 0; mi < 4; ++mi) {
      int m = mi*16 + lr;
      int hm = ((m & 7) ^ ((m >> 3) & 7)) << 4;
      af[mi] = *(const f16x8*)(wl + m*128 + ((ks*64 + lg*16) ^ hm));
    }
    #pragma unroll
    for (int ni = 0; ni < 4; ++ni) {
      int p = n0 + ni*16 + lr;
      int hp = ((p & 7) ^ ((p >> 3) & 7)) << 4;
      bfr[ni] = *(const f16x8*)(xs + p*128 + ((ks*64 + lg*16) ^ hp));
    }
    #pragma unroll
    for (int mi = 0; mi < 4; ++mi)
      #pragma unroll
      for (int ni = 0; ni < 4; ++ni)
        acc[mi][ni] = __builtin_amdgcn_mfma_f32_16x16x32_f16(
            af[mi], bfr[ni], acc[mi][ni], 0, 0, 0);
  }

  // D: col(=pos) = lane&15, row(=co) = (lane>>4)*4 + r; direct f32 stores.
  const long long obase = (long long)b*64*HW + (long long)y*256;
  #pragma unroll
  for (int mi = 0; mi < 4; ++mi)
    #pragma unroll
    for (int ni = 0; ni < 4; ++ni)
      #pragma unroll
      for (int r = 0; r < 4; ++r) {
        int m = mi*16 + lg*4 + r;
        int p = n0 + ni*16 + lr;
        out[obase + (long long)m*HW + p] = acc[mi][ni][r];
      }
}

// ---------------------------------------------------------------------------
extern "C" void kernel_launch(void* const* d_in, const int* in_sizes, int n_in,
                              void* d_out, int out_size, void* d_ws, size_t ws_size,
                              hipStream_t stream)
{
  float* out = (float*)d_out;

  int mp[7] = {-1,-1,-1,-1,-1,-1,-1};
  bool ok = (n_in == 7);
  if (ok) {
    int n4 = 0;
    for (int i = 0; i < 7; ++i) {
      long s = in_sizes[i];
      if      (s == 33554432) mp[0] = i;            // x
      else if (s == 576)      mp[2] = i;            // w_gate_dw
      else if (s == 12288)    mp[3] = i;            // w_qkv
      else if (s == 1728)     mp[4] = i;            // w_qkv_dw
      else if (s == 8)        mp[6] = i;            // temperature
      else if (s == 4096)     { if (n4 == 0) mp[1] = i; else mp[5] = i; ++n4; }
    }
    ok = ok && (n4 == 2);
    for (int i = 0; i < 7; ++i) ok = ok && (mp[i] >= 0);
  }
  if (!ok) { k_signal<<<2048,256,0,stream>>>(out, (long long)out_size, 2000.0f); return; }
  if (out_size != 33554432) { k_signal<<<2048,256,0,stream>>>(out, (long long)out_size, 3000.0f); return; }

  const float* x    = (const float*)d_in[mp[0]];
  const float* wg   = (const float*)d_in[mp[1]];
  const float* wgd  = (const float*)d_in[mp[2]];
  const float* wqkv = (const float*)d_in[mp[3]];
  const float* wqd  = (const float*)d_in[mp[4]];
  const float* wpj  = (const float*)d_in[mp[5]];
  const float* tp   = (const float*)d_in[mp[6]];

  unsigned char* ws = (unsigned char*)d_ws;
  const size_t GRP_SZ   = 8UL*8*NBAND*80*4;
  const size_t FULL     = 402653184UL + GRP_SZ + 16384UL;
  const size_t PERB_GRP = 8UL*NBAND*80*4;
  const size_t PERB     = 50331648UL + PERB_GRP + 2048UL;

  if (ws != nullptr && ws_size >= FULL) {
    f16*   A    = (f16*)ws;
    f16*   Vv   = (f16*)(ws + 268435456UL);
    f16*   GG   = (f16*)(ws + 335544320UL);
    float* GRP  = (float*)(ws + 402653184UL);
    float* ATT  = (float*)(ws + 402653184UL + GRP_SZ);
    k1_mfma <<<8192, 256, 0, stream>>>(x, wg, wqkv, A);
    k2a_dw  <<<4096, 256, 0, stream>>>(A, wgd, wqd, Vv, GG);
    k2b_qk  <<<8*8*NBAND, 64, 0, stream>>>(A, wqd, GRP);
    k2c_attn<<<64,   64,  0, stream>>>(GRP, tp, ATT);
    k3_out  <<<2048, 256, 0, stream>>>(Vv, GG, ATT, wpj, out);
  } else if (ws != nullptr && ws_size >= PERB) {
    f16*   A    = (f16*)ws;
    f16*   Vv   = (f16*)(ws + 33554432UL);
    f16*   GG   = (f16*)(ws + 41943040UL);
    float* GRP  = (float*)(ws + 50331648UL);
    float* ATT  = (float*)(ws + 50331648UL + PERB_GRP);
    for (int b = 0; b < 8; ++b) {
      const float* xb = x + (long long)b*64*HW;
      float* ob = out + (long long)b*64*HW;
      k1_mfma <<<1024, 256, 0, stream>>>(xb, wg, wqkv, A);
      k2a_dw  <<<512,  256, 0, stream>>>(A, wgd, wqd, Vv, GG);
      k2b_qk  <<<8*NBAND, 64, 0, stream>>>(A, wqd, GRP);
      k2c_attn<<<8,    64,  0, stream>>>(GRP, tp, ATT);
      k3_out  <<<256,  256, 0, stream>>>(Vv, GG, ATT, wpj, ob);
    }
  } else {
    k_signal<<<2048,256,0,stream>>>(out, (long long)out_size, 1000.0f);
  }
}

// Round 13
// 337.246 us; speedup vs baseline: 4.2348x; 1.0508x over previous
//
#include <hip/hip_runtime.h>

typedef _Float16 f16;
using f16x4 = __attribute__((ext_vector_type(4))) _Float16;
using f16x8 = __attribute__((ext_vector_type(8))) _Float16;
using f32x4 = __attribute__((ext_vector_type(4))) float;

#define HW 65536
#define NBAND 16
#define ROWS 16
#define RS 320   // k2b ring row stride in f16

// own erf (A&S 7.1.26, |err| <= 1.5e-7); __expf is HW v_exp_f32
static __device__ __forceinline__ float my_erf(float v) {
  float x = fabsf(v);
  float t = 1.f / (1.f + 0.3275911f * x);
  float y = t * (0.254829592f + t * (-0.284496736f + t * (1.421413741f
          + t * (-1.453152027f + t * 1.061405429f))));
  float r = 1.f - y * __expf(-x * x);
  return v < 0.f ? -r : r;
}
static __device__ __forceinline__ float my_gelu(float s) {
  return 0.5f * s * (1.f + my_erf(s * 0.70710678118654752f));
}

__global__ void TRA_Attention_15281493639325_kernel() {}

__global__ void k_signal(float* out, long long n, float val) {
  long long i = (long long)blockIdx.x * blockDim.x + threadIdx.x;
  long long stride = (long long)gridDim.x * blockDim.x;
  for (; i < n; i += stride) out[i] = val;
}

// ---------------------------------------------------------------------------
// K0: one-time weight convert f32 -> f16, plain [256 out][64 in] layout.
// grid = 16 x 256 thr.
// ---------------------------------------------------------------------------
__global__ __launch_bounds__(256) void k0_wconv(
    const float* __restrict__ w_gate, const float* __restrict__ w_qkv,
    f16* __restrict__ W16)
{
  int i = blockIdx.x * 256 + threadIdx.x;     // 0..4095, 4 elems each
  int m = i >> 4, kc = i & 15;
  const float* src = (m < 64) ? (w_gate + m*64 + kc*4)
                              : (w_qkv + (m-64)*64 + kc*4);
  float4 f = *(const float4*)src;
  f16x4 pk = { (f16)f.x, (f16)f.y, (f16)f.z, (f16)f.w };
  *(f16x4*)(W16 + m*64 + kc*4) = pk;
}

// ---------------------------------------------------------------------------
// K1 (MFMA f16): fused 1x1 conv, 256 out ch. Tile M=256 x N=64 pos, K=64.
// Weights read as fragments straight from W16 (32KB, L1-resident) — no W LDS,
// no per-block converts. LDS 32KB total: xs (8KB, pre-MFMA) aliased inside
// the 32KB epilogue tile (post-barrier), stride-64 + chunk-XOR.
// grid = nb*1024.
// ---------------------------------------------------------------------------
__global__ __launch_bounds__(256) void k1_mfma(
    const float* __restrict__ x, const f16* __restrict__ W16,
    f16* __restrict__ A)
{
  __shared__ __align__(16) unsigned char lds[32768];
  unsigned char* xs = lds;        // xT: 64 pos-rows x 128B, XOR-swizzled
  f16* os = (f16*)lds;            // epilogue: [256 ch][64 pos], chunk-XOR

  const int tid = threadIdx.x, blk = blockIdx.x;
  const int b = blk >> 10;
  const long long p0 = (long long)(blk & 1023) * 64;

  // stage x tile transposed: xs[p][k], f32 -> f16
  for (int cid = tid; cid < 1024; cid += 256) {
    int k = cid >> 4, c = cid & 15;
    float4 f = *(const float4*)(x + ((long long)b*64 + k)*HW + p0 + c*4);
    const float* e = (const float*)&f;
    #pragma unroll
    for (int i = 0; i < 4; ++i) {
      int p = c*4 + i;
      int hp = ((p & 7) ^ ((p >> 3) & 7)) << 4;
      *(f16*)(xs + p*128 + ((2*k) ^ hp)) = (f16)e[i];
    }
  }
  __syncthreads();

  const int wave = tid >> 6, lane = tid & 63;
  const int m0 = (wave >> 1) * 128, n0 = (wave & 1) * 32;
  const int lr = lane & 15, lg = lane >> 4;

  f32x4 acc[8][2];
  #pragma unroll
  for (int i = 0; i < 8; ++i)
    #pragma unroll
    for (int j = 0; j < 2; ++j) acc[i][j] = (f32x4){0.f,0.f,0.f,0.f};

  #pragma unroll
  for (int ks = 0; ks < 2; ++ks) {
    f16x8 af[8], bfr[2];
    #pragma unroll
    for (int mi = 0; mi < 8; ++mi) {
      int m = m0 + mi*16 + lr;
      af[mi] = *(const f16x8*)(W16 + m*64 + ks*32 + lg*8);  // L1-hot
    }
    #pragma unroll
    for (int ni = 0; ni < 2; ++ni) {
      int p = n0 + ni*16 + lr;
      int hp = ((p & 7) ^ ((p >> 3) & 7)) << 4;
      bfr[ni] = *(const f16x8*)(xs + p*128 + ((ks*64 + lg*16) ^ hp));
    }
    #pragma unroll
    for (int mi = 0; mi < 8; ++mi)
      #pragma unroll
      for (int ni = 0; ni < 2; ++ni)
        acc[mi][ni] = __builtin_amdgcn_mfma_f32_16x16x32_f16(
            af[mi], bfr[ni], acc[mi][ni], 0, 0, 0);
  }

  // all xs ds_reads consumed (lgkm waits before MFMA); barrier, reuse LDS.
  __syncthreads();
  #pragma unroll
  for (int mi = 0; mi < 8; ++mi)
    #pragma unroll
    for (int ni = 0; ni < 2; ++ni)
      #pragma unroll
      for (int r = 0; r < 4; ++r) {
        int m = m0 + mi*16 + lg*4 + r;
        int p = n0 + ni*16 + lr;
        os[m*64 + (p ^ ((m & 7) << 3))] = (f16)acc[mi][ni][r];
      }
  __syncthreads();

  // coalesced stores: 8 passes x 256 thr x f16x8; 8 threads cover one row.
  #pragma unroll
  for (int pass = 0; pass < 8; ++pass) {
    int idx = pass*256 + tid;
    int row = idx >> 3, c8 = idx & 7;
    f16x8 v = *(const f16x8*)(lds + row*128 + ((c8 ^ (row & 7)) * 16));
    *(f16x8*)(A + ((long long)b*256 + row)*HW + p0 + c8*8) = v;
  }
}

// ---------------------------------------------------------------------------
// K2a (reg-rolling, LDS-free): depthwise 3x3 for gate (+GELU) and v channels.
// ---------------------------------------------------------------------------
__global__ __launch_bounds__(256) void k2a_dw(
    const f16* __restrict__ A, const float* __restrict__ w_gate_dw,
    const float* __restrict__ w_qkv_dw, f16* __restrict__ Vv, f16* __restrict__ GG)
{
  const int tid = threadIdx.x, blk = blockIdx.x;
  const int yband = blk & 3, ch2 = (blk >> 2) & 127, b = blk >> 9;
  const bool isv = ch2 >= 64;
  const int c = isv ? ch2 - 64 : ch2;
  const f16* src = A + ((long long)b*256 + (isv ? 192 + c : c)) * HW;
  const float* wsrc = isv ? (w_qkv_dw + (128 + c)*9) : (w_gate_dw + c*9);
  f16* dst = (isv ? Vv : GG) + ((long long)b*64 + c) * HW;

  float wd[9];
  #pragma unroll
  for (int j = 0; j < 9; ++j) wd[j] = wsrc[j];

  const int xc = tid & 31, ysub = tid >> 5;
  const int lane = tid & 63;
  const int xbase = xc * 8;
  const int y0 = yband * 64 + ysub * 8;

  float rb[3][10];

  auto load_row = [&](int y, float* r) {
    if (y >= 0 && y < 256) {
      uint4 raw = *(const uint4*)(src + y*256 + xbase);
      const f16* e = (const f16*)&raw;
      #pragma unroll
      for (int t = 0; t < 8; ++t) r[1 + t] = (float)e[t];
    } else {
      #pragma unroll
      for (int t = 0; t < 8; ++t) r[1 + t] = 0.f;
    }
    float lf = __shfl(r[8], lane - 1);
    float rf = __shfl(r[1], lane + 1);
    r[0] = (xc == 0)  ? 0.f : lf;
    r[9] = (xc == 31) ? 0.f : rf;
  };

  load_row(y0 - 1, rb[0]);
  load_row(y0,     rb[1]);

  #pragma unroll
  for (int i = 0; i < 8; ++i) {
    load_row(y0 + i + 1, rb[(i + 2) % 3]);
    const float* rm = rb[i % 3];
    const float* r0 = rb[(i + 1) % 3];
    const float* rp = rb[(i + 2) % 3];
    f16x8 st;
    #pragma unroll
    for (int j = 0; j < 8; ++j) {
      float s = wd[0]*rm[j] + wd[1]*rm[j+1] + wd[2]*rm[j+2]
              + wd[3]*r0[j] + wd[4]*r0[j+1] + wd[5]*r0[j+2]
              + wd[6]*rp[j] + wd[7]*rp[j+1] + wd[8]*rp[j+2];
      if (!isv) s = my_gelu(s);
      st[j] = (f16)s;
    }
    *(f16x8*)(dst + (y0 + i)*256 + xbase) = st;
  }
}

// ---------------------------------------------------------------------------
// K2b (MFMA gram): dwconv for q,k of one head fused with 16x16 gram via
// mfma_f32_16x16x32_f16 with identical A/B fragments. 1 wave per
// (b,h,16-row band). GRP layout: [b][h][band][80] = qq[8], kk[8], qk[64].
// ---------------------------------------------------------------------------
__device__ __forceinline__ int ridx(int c, int slot, int i) {
  return ((((c << 2) | slot) * RS) + i) ^ ((c & 7) << 3);
}

__global__ __launch_bounds__(64) void k2b_qk(
    const f16* __restrict__ A, const float* __restrict__ w_qkv_dw,
    float* __restrict__ GRP)
{
  __shared__ __align__(16) f16 ring[16*4*RS];
  const int lane = threadIdx.x, blk = blockIdx.x;
  const int band = blk & (NBAND-1), h = (blk >> 4) & 7, b = blk >> 7;

  const int c  = lane & 15, g  = lane >> 4;
  const int cs = lane >> 2, q4 = lane & 3;

  const int wrow = (c < 8) ? (h*8 + c) : (64 + h*8 + (c - 8));
  float wq[9];
  #pragma unroll
  for (int j = 0; j < 9; ++j) wq[j] = w_qkv_dw[wrow*9 + j];

  const f16* sbase = A + ((long long)b*256 +
      (cs < 8 ? 64 + h*8 + cs : 128 + h*8 + (cs - 8))) * HW;

  ring[ridx(cs, q4, 7)]   = (f16)0.f;
  ring[ridx(cs, q4, 264)] = (f16)0.f;

  auto load_row = [&](int yy, uint4* r) {
    if (yy >= 0 && yy < 256) {
      const f16* p = sbase + yy*256 + q4*64;
      #pragma unroll
      for (int t = 0; t < 8; ++t) r[t] = *(const uint4*)(p + t*8);
    } else {
      #pragma unroll
      for (int t = 0; t < 8; ++t) r[t] = make_uint4(0u,0u,0u,0u);
    }
  };
  auto write_row = [&](int slot, const uint4* r) {
    #pragma unroll
    for (int t = 0; t < 8; ++t)
      *(uint4*)&ring[ridx(cs, slot, 8 + q4*64 + t*8)] = r[t];
  };

  const int y0 = band * ROWS;
  {
    uint4 r[8];
    load_row(y0-1, r); write_row((y0+3)&3, r);
    load_row(y0,   r); write_row((y0+4)&3, r);
    load_row(y0+1, r); write_row((y0+5)&3, r);
  }
  __syncthreads();

  f32x4 acc = (f32x4){0.f, 0.f, 0.f, 0.f};

  for (int y = y0; y < y0 + ROWS; ++y) {
    uint4 r[8];
    const bool pf = (y + 2 <= y0 + ROWS);
    if (pf) load_row(y + 2, r);

    const int s0 = (y+3)&3, s1 = (y+4)&3, s2 = (y+5)&3;
    #pragma unroll
    for (int q = 0; q < 8; ++q) {
      const int base = 7 + q*32 + g*8;
      float v0[10], v1[10], v2[10];
      #pragma unroll
      for (int t = 0; t < 10; ++t) {
        v0[t] = (float)ring[ridx(c, s0, base+t)];
        v1[t] = (float)ring[ridx(c, s1, base+t)];
        v2[t] = (float)ring[ridx(c, s2, base+t)];
      }
      f16x8 frag;
      #pragma unroll
      for (int j = 0; j < 8; ++j) {
        float s = wq[0]*v0[j] + wq[1]*v0[j+1] + wq[2]*v0[j+2]
                + wq[3]*v1[j] + wq[4]*v1[j+1] + wq[5]*v1[j+2]
                + wq[6]*v2[j] + wq[7]*v2[j+1] + wq[8]*v2[j+2];
        frag[j] = (f16)s;
      }
      acc = __builtin_amdgcn_mfma_f32_16x16x32_f16(frag, frag, acc, 0, 0, 0);
    }
    if (pf) write_row((y+6)&3, r);
    __syncthreads();
  }

  const long long gbase = (long long)((b*8 + h)*NBAND + band) * 80;
  #pragma unroll
  for (int reg = 0; reg < 4; ++reg) {
    int rrow = g*4 + reg;
    float val = acc[reg];
    if (rrow == c) GRP[gbase + c] = val;
    else if (rrow < 8 && c >= 8) GRP[gbase + 16 + rrow*8 + (c-8)] = val;
  }
}

// ---------------------------------------------------------------------------
// K2c: reduce band partials, normalize, temperature, softmax. grid = nb*8
// ---------------------------------------------------------------------------
__global__ __launch_bounds__(64) void k2c_attn(
    const float* __restrict__ GRP, const float* __restrict__ temp,
    float* __restrict__ ATT)
{
  __shared__ float s[80];
  const int tid = threadIdx.x;
  const int h = blockIdx.x & 7, b = blockIdx.x >> 3;
  for (int i = tid; i < 80; i += 64) {
    float v = 0.f;
    for (int band = 0; band < NBAND; ++band)
      v += GRP[(((b*8 + h)*NBAND + band) * 80) + i];
    s[i] = v;
  }
  __syncthreads();
  const int c = tid >> 3, d = tid & 7;
  float nq = fmaxf(sqrtf(s[c]), 1e-12f);
  float nk = fmaxf(sqrtf(s[8 + d]), 1e-12f);
  float logit = s[16 + c*8 + d] / (nq * nk) * temp[h];
  float m = logit;
  #pragma unroll
  for (int off = 4; off; off >>= 1) m = fmaxf(m, __shfl_xor(m, off));
  float e = __expf(logit - m);
  float sum = e;
  #pragma unroll
  for (int off = 4; off; off >>= 1) sum += __shfl_xor(sum, off);
  ATT[((b*8 + h)*8 + c)*8 + d] = e / sum;
}

// ---------------------------------------------------------------------------
// K3 (MFMA proj): g = gelu(gate)*(attn@v) -> f16 LDS tile -> MFMA with
// w_proj (f16) -> f32 out. Block = 256 thr, one image row (256 pos).
// grid = nb*256.
// ---------------------------------------------------------------------------
__global__ __launch_bounds__(256) void k3_out(
    const f16* __restrict__ Vv, const f16* __restrict__ GG,
    const float* __restrict__ ATT, const float* __restrict__ w_proj,
    float* __restrict__ out)
{
  __shared__ __align__(16) unsigned char lds[64*128 + 256*128 + 2048];
  unsigned char* wl = lds;                    // wp f16 [64co][64ch] swz rows
  unsigned char* xs = lds + 64*128;           // g  f16 [256pos][64ch] swz rows
  float* attn_s = (float*)(lds + 64*128 + 256*128);

  const int tid = threadIdx.x;
  const int y = blockIdx.x & 255, b = blockIdx.x >> 8;

  for (int cid = tid; cid < 1024; cid += 256) {
    int m = cid >> 4, kc = cid & 15;
    float4 f = *(const float4*)(w_proj + m*64 + kc*4);
    int hm = ((m & 7) ^ ((m >> 3) & 7)) << 4;
    f16x4 pk = { (f16)f.x, (f16)f.y, (f16)f.z, (f16)f.w };
    *(f16x4*)(wl + m*128 + ((kc*8) ^ hm)) = pk;
  }
  for (int i = tid; i < 512; i += 256) attn_s[i] = ATT[b*512 + i];
  __syncthreads();

  {
    const int pg = tid & 31, hd = tid >> 5;
    const long long base = ((long long)b*64 + hd*8)*HW + (long long)y*256 + pg*8;
    f16x8 vv[8], gg[8];
    #pragma unroll
    for (int d = 0; d < 8; ++d)
      vv[d] = *(const f16x8*)(Vv + base + (long long)d*HW);
    #pragma unroll
    for (int c = 0; c < 8; ++c)
      gg[c] = *(const f16x8*)(GG + base + (long long)c*HW);
    float a[8][8];
    #pragma unroll
    for (int c = 0; c < 8; ++c)
      #pragma unroll
      for (int d = 0; d < 8; ++d) a[c][d] = attn_s[hd*64 + c*8 + d];
    #pragma unroll
    for (int j = 0; j < 8; ++j) {
      int p = pg*8 + j;
      int hp = ((p & 7) ^ ((p >> 3) & 7)) << 4;
      f16x8 st;
      #pragma unroll
      for (int c = 0; c < 8; ++c) {
        float av = 0.f;
        #pragma unroll
        for (int d = 0; d < 8; ++d) av += a[c][d] * (float)vv[d][j];
        st[c] = (f16)((float)gg[c][j] * av);
      }
      *(f16x8*)(xs + p*128 + ((hd*16) ^ hp)) = st;
    }
  }
  __syncthreads();

  const int wave = tid >> 6, lane = tid & 63;
  const int n0 = wave * 64;
  const int lr = lane & 15, lg = lane >> 4;

  f32x4 acc[4][4];
  #pragma unroll
  for (int i = 0; i < 4; ++i)
    #pragma unroll
    for (int j = 0; j < 4; ++j) acc[i][j] = (f32x4){0.f,0.f,0.f,0.f};

  #pragma unroll
  for (int ks = 0; ks < 2; ++ks) {
    f16x8 af[4], bfr[4];
    #pragma unroll
    for (int mi = 0; mi < 4; ++mi) {
      int m = mi*16 + lr;
      int hm = ((m & 7) ^ ((m >> 3) & 7)) << 4;
      af[mi] = *(const f16x8*)(wl + m*128 + ((ks*64 + lg*16) ^ hm));
    }
    #pragma unroll
    for (int ni = 0; ni < 4; ++ni) {
      int p = n0 + ni*16 + lr;
      int hp = ((p & 7) ^ ((p >> 3) & 7)) << 4;
      bfr[ni] = *(const f16x8*)(xs + p*128 + ((ks*64 + lg*16) ^ hp));
    }
    #pragma unroll
    for (int mi = 0; mi < 4; ++mi)
      #pragma unroll
      for (int ni = 0; ni < 4; ++ni)
        acc[mi][ni] = __builtin_amdgcn_mfma_f32_16x16x32_f16(
            af[mi], bfr[ni], acc[mi][ni], 0, 0, 0);
  }

  const long long obase = (long long)b*64*HW + (long long)y*256;
  #pragma unroll
  for (int mi = 0; mi < 4; ++mi)
    #pragma unroll
    for (int ni = 0; ni < 4; ++ni)
      #pragma unroll
      for (int r = 0; r < 4; ++r) {
        int m = mi*16 + lg*4 + r;
        int p = n0 + ni*16 + lr;
        out[obase + (long long)m*HW + p] = acc[mi][ni][r];
      }
}

// ---------------------------------------------------------------------------
extern "C" void kernel_launch(void* const* d_in, const int* in_sizes, int n_in,
                              void* d_out, int out_size, void* d_ws, size_t ws_size,
                              hipStream_t stream)
{
  float* out = (float*)d_out;

  int mp[7] = {-1,-1,-1,-1,-1,-1,-1};
  bool ok = (n_in == 7);
  if (ok) {
    int n4 = 0;
    for (int i = 0; i < 7; ++i) {
      long s = in_sizes[i];
      if      (s == 33554432) mp[0] = i;            // x
      else if (s == 576)      mp[2] = i;            // w_gate_dw
      else if (s == 12288)    mp[3] = i;            // w_qkv
      else if (s == 1728)     mp[4] = i;            // w_qkv_dw
      else if (s == 8)        mp[6] = i;            // temperature
      else if (s == 4096)     { if (n4 == 0) mp[1] = i; else mp[5] = i; ++n4; }
    }
    ok = ok && (n4 == 2);
    for (int i = 0; i < 7; ++i) ok = ok && (mp[i] >= 0);
  }
  if (!ok) { k_signal<<<2048,256,0,stream>>>(out, (long long)out_size, 2000.0f); return; }
  if (out_size != 33554432) { k_signal<<<2048,256,0,stream>>>(out, (long long)out_size, 3000.0f); return; }

  const float* x    = (const float*)d_in[mp[0]];
  const float* wg   = (const float*)d_in[mp[1]];
  const float* wgd  = (const float*)d_in[mp[2]];
  const float* wqkv = (const float*)d_in[mp[3]];
  const float* wqd  = (const float*)d_in[mp[4]];
  const float* wpj  = (const float*)d_in[mp[5]];
  const float* tp   = (const float*)d_in[mp[6]];

  unsigned char* ws = (unsigned char*)d_ws;
  const size_t GRP_SZ   = 8UL*8*NBAND*80*4;
  const size_t FULL     = 402653184UL + GRP_SZ + 16384UL + 32768UL;
  const size_t PERB_GRP = 8UL*NBAND*80*4;
  const size_t PERB     = 50331648UL + PERB_GRP + 2048UL + 32768UL;

  if (ws != nullptr && ws_size >= FULL) {
    f16*   A    = (f16*)ws;
    f16*   Vv   = (f16*)(ws + 268435456UL);
    f16*   GG   = (f16*)(ws + 335544320UL);
    float* GRP  = (float*)(ws + 402653184UL);
    float* ATT  = (float*)(ws + 402653184UL + GRP_SZ);
    f16*   W16  = (f16*)(ws + 402653184UL + GRP_SZ + 16384UL);
    k0_wconv<<<16,   256, 0, stream>>>(wg, wqkv, W16);
    k1_mfma <<<8192, 256, 0, stream>>>(x, W16, A);
    k2a_dw  <<<4096, 256, 0, stream>>>(A, wgd, wqd, Vv, GG);
    k2b_qk  <<<8*8*NBAND, 64, 0, stream>>>(A, wqd, GRP);
    k2c_attn<<<64,   64,  0, stream>>>(GRP, tp, ATT);
    k3_out  <<<2048, 256, 0, stream>>>(Vv, GG, ATT, wpj, out);
  } else if (ws != nullptr && ws_size >= PERB) {
    f16*   A    = (f16*)ws;
    f16*   Vv   = (f16*)(ws + 33554432UL);
    f16*   GG   = (f16*)(ws + 41943040UL);
    float* GRP  = (float*)(ws + 50331648UL);
    float* ATT  = (float*)(ws + 50331648UL + PERB_GRP);
    f16*   W16  = (f16*)(ws + 50331648UL + PERB_GRP + 2048UL);
    k0_wconv<<<16, 256, 0, stream>>>(wg, wqkv, W16);
    for (int b = 0; b < 8; ++b) {
      const float* xb = x + (long long)b*64*HW;
      float* ob = out + (long long)b*64*HW;
      k1_mfma <<<1024, 256, 0, stream>>>(xb, W16, A);
      k2a_dw  <<<512,  256, 0, stream>>>(A, wgd, wqd, Vv, GG);
      k2b_qk  <<<8*NBAND, 64, 0, stream>>>(A, wqd, GRP);
      k2c_attn<<<8,    64,  0, stream>>>(GRP, tp, ATT);
      k3_out  <<<256,  256, 0, stream>>>(Vv, GG, ATT, wpj, ob);
    }
  } else {
    k_signal<<<2048,256,0,stream>>>(out, (long long)out_size, 1000.0f);
  }
}

// Round 15
// 287.677 us; speedup vs baseline: 4.9645x; 1.1723x over previous
//
#include <hip/hip_runtime.h>

typedef _Float16 f16;
using f16x4 = __attribute__((ext_vector_type(4))) _Float16;
using f16x8 = __attribute__((ext_vector_type(8))) _Float16;
using f32x4 = __attribute__((ext_vector_type(4))) float;

#define HW 65536
#define NBAND 16
#define ROWS 16
#define RS 320   // k2b ring row stride in f16

// own erf (A&S 7.1.26, |err| <= 1.5e-7); __expf is HW v_exp_f32
static __device__ __forceinline__ float my_erf(float v) {
  float x = fabsf(v);
  float t = 1.f / (1.f + 0.3275911f * x);
  float y = t * (0.254829592f + t * (-0.284496736f + t * (1.421413741f
          + t * (-1.453152027f + t * 1.061405429f))));
  float r = 1.f - y * __expf(-x * x);
  return v < 0.f ? -r : r;
}
static __device__ __forceinline__ float my_gelu(float s) {
  return 0.5f * s * (1.f + my_erf(s * 0.70710678118654752f));
}

__global__ void TRA_Attention_15281493639325_kernel() {}

__global__ void k_signal(float* out, long long n, float val) {
  long long i = (long long)blockIdx.x * blockDim.x + threadIdx.x;
  long long stride = (long long)gridDim.x * blockDim.x;
  for (; i < n; i += stride) out[i] = val;
}

// ---------------------------------------------------------------------------
// K0: one-time weight convert f32 -> f16, plain [256 out][64 in] layout.
// ---------------------------------------------------------------------------
__global__ __launch_bounds__(256) void k0_wconv(
    const float* __restrict__ w_gate, const float* __restrict__ w_qkv,
    f16* __restrict__ W16)
{
  int i = blockIdx.x * 256 + threadIdx.x;     // 0..4095, 4 elems each
  int m = i >> 4, kc = i & 15;
  const float* src = (m < 64) ? (w_gate + m*64 + kc*4)
                              : (w_qkv + (m-64)*64 + kc*4);
  float4 f = *(const float4*)src;
  f16x4 pk = { (f16)f.x, (f16)f.y, (f16)f.z, (f16)f.w };
  *(f16x4*)(W16 + m*64 + kc*4) = pk;
}

// ---------------------------------------------------------------------------
// K1 (MFMA f16, T14 pipeline): fused 1x1 conv, 256 out ch.
// Persistent block = one image row (256 pos) = 4 tiles of 64 pos.
// Per tile: regs->xs, barrier, ISSUE next-tile global loads (early), MFMA
// (weights from L1-resident W16), barrier, acc->os, barrier, coalesced store,
// barrier (tile fully isolated — kills the stage/store overlap window that
// is the prime suspect for round-14's replay divergence).
// LDS 40KB: xs 8KB + os 32KB. grid = nb*256.
// ---------------------------------------------------------------------------
__global__ __launch_bounds__(256) void k1_mfma(
    const float* __restrict__ x, const f16* __restrict__ W16,
    f16* __restrict__ A)
{
  __shared__ __align__(16) unsigned char xs[8192];    // xT 64 pos x 128B swz
  __shared__ __align__(16) f16 os[256*64];            // epilogue tile 32KB

  const int tid = threadIdx.x, blk = blockIdx.x;
  const int b = blk >> 8;
  const long long row0 = (long long)(blk & 255) * 256;

  const int wave = tid >> 6, lane = tid & 63;
  const int m0 = (wave >> 1) * 128, n0 = (wave & 1) * 32;
  const int lr = lane & 15, lg = lane >> 4;

  float4 pre[4];
  #pragma unroll
  for (int i = 0; i < 4; ++i) {
    int cid = tid + (i << 8), k = cid >> 4, c = cid & 15;
    pre[i] = *(const float4*)(x + ((long long)b*64 + k)*HW + row0 + c*4);
  }

  for (int t = 0; t < 4; ++t) {
    const long long p0 = row0 + t*64;

    // stage regs -> xs (f32 -> f16, XOR-swizzled)
    #pragma unroll
    for (int i = 0; i < 4; ++i) {
      int cid = tid + (i << 8), k = cid >> 4, c = cid & 15;
      const float* e = (const float*)&pre[i];
      #pragma unroll
      for (int j = 0; j < 4; ++j) {
        int p = c*4 + j;
        int hp = ((p & 7) ^ ((p >> 3) & 7)) << 4;
        *(f16*)(xs + p*128 + ((2*k) ^ hp)) = (f16)e[j];
      }
    }
    __syncthreads();                       // barrier 1: xs ready

    if (t < 3) {                           // issue next-tile loads EARLY (T14)
      const long long pn = row0 + (t+1)*64;
      #pragma unroll
      for (int i = 0; i < 4; ++i) {
        int cid = tid + (i << 8), k = cid >> 4, c = cid & 15;
        pre[i] = *(const float4*)(x + ((long long)b*64 + k)*HW + pn + c*4);
      }
    }

    f32x4 acc[8][2];
    #pragma unroll
    for (int i = 0; i < 8; ++i)
      #pragma unroll
      for (int j = 0; j < 2; ++j) acc[i][j] = (f32x4){0.f,0.f,0.f,0.f};

    #pragma unroll
    for (int ks = 0; ks < 2; ++ks) {
      f16x8 af[8], bfr[2];
      #pragma unroll
      for (int mi = 0; mi < 8; ++mi) {
        int m = m0 + mi*16 + lr;
        af[mi] = *(const f16x8*)(W16 + m*64 + ks*32 + lg*8);  // L1-hot
      }
      #pragma unroll
      for (int ni = 0; ni < 2; ++ni) {
        int p = n0 + ni*16 + lr;
        int hp = ((p & 7) ^ ((p >> 3) & 7)) << 4;
        bfr[ni] = *(const f16x8*)(xs + p*128 + ((ks*64 + lg*16) ^ hp));
      }
      #pragma unroll
      for (int mi = 0; mi < 8; ++mi)
        #pragma unroll
        for (int ni = 0; ni < 2; ++ni)
          acc[mi][ni] = __builtin_amdgcn_mfma_f32_16x16x32_f16(
              af[mi], bfr[ni], acc[mi][ni], 0, 0, 0);
    }
    __syncthreads();                       // barrier 2: xs reads done

    #pragma unroll
    for (int mi = 0; mi < 8; ++mi)
      #pragma unroll
      for (int ni = 0; ni < 2; ++ni)
        #pragma unroll
        for (int r = 0; r < 4; ++r) {
          int m = m0 + mi*16 + lg*4 + r;
          int p = n0 + ni*16 + lr;
          os[m*64 + (p ^ ((m & 7) << 3))] = (f16)acc[mi][ni][r];
        }
    __syncthreads();                       // barrier 3: os written

    // coalesced stores: 8 passes x 256 thr x f16x8
    #pragma unroll
    for (int pass = 0; pass < 8; ++pass) {
      int idx = pass*256 + tid;
      int row = idx >> 3, c8 = idx & 7;
      f16x8 v = *(const f16x8*)((const unsigned char*)os + row*128
                                + ((c8 ^ (row & 7)) * 16));
      *(f16x8*)(A + ((long long)b*256 + row)*HW + p0 + c8*8) = v;
    }
    __syncthreads();                       // barrier 4: tile isolated
  }
}

// ---------------------------------------------------------------------------
// K2a (reg-rolling, LDS-free): depthwise 3x3 for gate (+GELU) and v channels.
// ---------------------------------------------------------------------------
__global__ __launch_bounds__(256) void k2a_dw(
    const f16* __restrict__ A, const float* __restrict__ w_gate_dw,
    const float* __restrict__ w_qkv_dw, f16* __restrict__ Vv, f16* __restrict__ GG)
{
  const int tid = threadIdx.x, blk = blockIdx.x;
  const int yband = blk & 3, ch2 = (blk >> 2) & 127, b = blk >> 9;
  const bool isv = ch2 >= 64;
  const int c = isv ? ch2 - 64 : ch2;
  const f16* src = A + ((long long)b*256 + (isv ? 192 + c : c)) * HW;
  const float* wsrc = isv ? (w_qkv_dw + (128 + c)*9) : (w_gate_dw + c*9);
  f16* dst = (isv ? Vv : GG) + ((long long)b*64 + c) * HW;

  float wd[9];
  #pragma unroll
  for (int j = 0; j < 9; ++j) wd[j] = wsrc[j];

  const int xc = tid & 31, ysub = tid >> 5;
  const int lane = tid & 63;
  const int xbase = xc * 8;
  const int y0 = yband * 64 + ysub * 8;

  float rb[3][10];

  auto load_row = [&](int y, float* r) {
    if (y >= 0 && y < 256) {
      uint4 raw = *(const uint4*)(src + y*256 + xbase);
      const f16* e = (const f16*)&raw;
      #pragma unroll
      for (int t = 0; t < 8; ++t) r[1 + t] = (float)e[t];
    } else {
      #pragma unroll
      for (int t = 0; t < 8; ++t) r[1 + t] = 0.f;
    }
    float lf = __shfl(r[8], lane - 1);
    float rf = __shfl(r[1], lane + 1);
    r[0] = (xc == 0)  ? 0.f : lf;
    r[9] = (xc == 31) ? 0.f : rf;
  };

  load_row(y0 - 1, rb[0]);
  load_row(y0,     rb[1]);

  #pragma unroll
  for (int i = 0; i < 8; ++i) {
    load_row(y0 + i + 1, rb[(i + 2) % 3]);
    const float* rm = rb[i % 3];
    const float* r0 = rb[(i + 1) % 3];
    const float* rp = rb[(i + 2) % 3];
    f16x8 st;
    #pragma unroll
    for (int j = 0; j < 8; ++j) {
      float s = wd[0]*rm[j] + wd[1]*rm[j+1] + wd[2]*rm[j+2]
              + wd[3]*r0[j] + wd[4]*r0[j+1] + wd[5]*r0[j+2]
              + wd[6]*rp[j] + wd[7]*rp[j+1] + wd[8]*rp[j+2];
      if (!isv) s = my_gelu(s);
      st[j] = (f16)s;
    }
    *(f16x8*)(dst + (y0 + i)*256 + xbase) = st;
  }
}

// ---------------------------------------------------------------------------
// K2b (MFMA gram): dwconv for q,k of one head fused with 16x16 gram via
// mfma_f32_16x16x32_f16 with identical A/B fragments. 1 wave per
// (b,h,16-row band). GRP layout: [b][h][band][80] = qq[8], kk[8], qk[64].
// ---------------------------------------------------------------------------
__device__ __forceinline__ int ridx(int c, int slot, int i) {
  return ((((c << 2) | slot) * RS) + i) ^ ((c & 7) << 3);
}

__global__ __launch_bounds__(64) void k2b_qk(
    const f16* __restrict__ A, const float* __restrict__ w_qkv_dw,
    float* __restrict__ GRP)
{
  __shared__ __align__(16) f16 ring[16*4*RS];
  const int lane = threadIdx.x, blk = blockIdx.x;
  const int band = blk & (NBAND-1), h = (blk >> 4) & 7, b = blk >> 7;

  const int c  = lane & 15, g  = lane >> 4;
  const int cs = lane >> 2, q4 = lane & 3;

  const int wrow = (c < 8) ? (h*8 + c) : (64 + h*8 + (c - 8));
  float wq[9];
  #pragma unroll
  for (int j = 0; j < 9; ++j) wq[j] = w_qkv_dw[wrow*9 + j];

  const f16* sbase = A + ((long long)b*256 +
      (cs < 8 ? 64 + h*8 + cs : 128 + h*8 + (cs - 8))) * HW;

  ring[ridx(cs, q4, 7)]   = (f16)0.f;
  ring[ridx(cs, q4, 264)] = (f16)0.f;

  auto load_row = [&](int yy, uint4* r) {
    if (yy >= 0 && yy < 256) {
      const f16* p = sbase + yy*256 + q4*64;
      #pragma unroll
      for (int t = 0; t < 8; ++t) r[t] = *(const uint4*)(p + t*8);
    } else {
      #pragma unroll
      for (int t = 0; t < 8; ++t) r[t] = make_uint4(0u,0u,0u,0u);
    }
  };
  auto write_row = [&](int slot, const uint4* r) {
    #pragma unroll
    for (int t = 0; t < 8; ++t)
      *(uint4*)&ring[ridx(cs, slot, 8 + q4*64 + t*8)] = r[t];
  };

  const int y0 = band * ROWS;
  {
    uint4 r[8];
    load_row(y0-1, r); write_row((y0+3)&3, r);
    load_row(y0,   r); write_row((y0+4)&3, r);
    load_row(y0+1, r); write_row((y0+5)&3, r);
  }
  __syncthreads();

  f32x4 acc = (f32x4){0.f, 0.f, 0.f, 0.f};

  for (int y = y0; y < y0 + ROWS; ++y) {
    uint4 r[8];
    const bool pf = (y + 2 <= y0 + ROWS);
    if (pf) load_row(y + 2, r);

    const int s0 = (y+3)&3, s1 = (y+4)&3, s2 = (y+5)&3;
    #pragma unroll
    for (int q = 0; q < 8; ++q) {
      const int base = 7 + q*32 + g*8;
      float v0[10], v1[10], v2[10];
      #pragma unroll
      for (int t = 0; t < 10; ++t) {
        v0[t] = (float)ring[ridx(c, s0, base+t)];
        v1[t] = (float)ring[ridx(c, s1, base+t)];
        v2[t] = (float)ring[ridx(c, s2, base+t)];
      }
      f16x8 frag;
      #pragma unroll
      for (int j = 0; j < 8; ++j) {
        float s = wq[0]*v0[j] + wq[1]*v0[j+1] + wq[2]*v0[j+2]
                + wq[3]*v1[j] + wq[4]*v1[j+1] + wq[5]*v1[j+2]
                + wq[6]*v2[j] + wq[7]*v2[j+1] + wq[8]*v2[j+2];
        frag[j] = (f16)s;
      }
      acc = __builtin_amdgcn_mfma_f32_16x16x32_f16(frag, frag, acc, 0, 0, 0);
    }
    if (pf) write_row((y+6)&3, r);
    __syncthreads();
  }

  const long long gbase = (long long)((b*8 + h)*NBAND + band) * 80;
  #pragma unroll
  for (int reg = 0; reg < 4; ++reg) {
    int rrow = g*4 + reg;
    float val = acc[reg];
    if (rrow == c) GRP[gbase + c] = val;
    else if (rrow < 8 && c >= 8) GRP[gbase + 16 + rrow*8 + (c-8)] = val;
  }
}

// ---------------------------------------------------------------------------
// K2c: reduce band partials, normalize, temperature, softmax. grid = nb*8
// ---------------------------------------------------------------------------
__global__ __launch_bounds__(64) void k2c_attn(
    const float* __restrict__ GRP, const float* __restrict__ temp,
    float* __restrict__ ATT)
{
  __shared__ float s[80];
  const int tid = threadIdx.x;
  const int h = blockIdx.x & 7, b = blockIdx.x >> 3;
  for (int i = tid; i < 80; i += 64) {
    float v = 0.f;
    for (int band = 0; band < NBAND; ++band)
      v += GRP[(((b*8 + h)*NBAND + band) * 80) + i];
    s[i] = v;
  }
  __syncthreads();
  const int c = tid >> 3, d = tid & 7;
  float nq = fmaxf(sqrtf(s[c]), 1e-12f);
  float nk = fmaxf(sqrtf(s[8 + d]), 1e-12f);
  float logit = s[16 + c*8 + d] / (nq * nk) * temp[h];
  float m = logit;
  #pragma unroll
  for (int off = 4; off; off >>= 1) m = fmaxf(m, __shfl_xor(m, off));
  float e = __expf(logit - m);
  float sum = e;
  #pragma unroll
  for (int off = 4; off; off >>= 1) sum += __shfl_xor(sum, off);
  ATT[((b*8 + h)*8 + c)*8 + d] = e / sum;
}

// ---------------------------------------------------------------------------
// K3 (MFMA proj): g = gelu(gate)*(attn@v) -> f16 LDS tile -> MFMA with
// w_proj (f16) -> f32 out. Block = 256 thr, one image row (256 pos).
// grid = nb*256.
// ---------------------------------------------------------------------------
__global__ __launch_bounds__(256) void k3_out(
    const f16* __restrict__ Vv, const f16* __restrict__ GG,
    const float* __restrict__ ATT, const float* __restrict__ w_proj,
    float* __restrict__ out)
{
  __shared__ __align__(16) unsigned char lds[64*128 + 256*128 + 2048];
  unsigned char* wl = lds;                    // wp f16 [64co][64ch] swz rows
  unsigned char* xs = lds + 64*128;           // g  f16 [256pos][64ch] swz rows
  float* attn_s = (float*)(lds + 64*128 + 256*128);

  const int tid = threadIdx.x;
  const int y = blockIdx.x & 255, b = blockIdx.x >> 8;

  for (int cid = tid; cid < 1024; cid += 256) {
    int m = cid >> 4, kc = cid & 15;
    float4 f = *(const float4*)(w_proj + m*64 + kc*4);
    int hm = ((m & 7) ^ ((m >> 3) & 7)) << 4;
    f16x4 pk = { (f16)f.x, (f16)f.y, (f16)f.z, (f16)f.w };
    *(f16x4*)(wl + m*128 + ((kc*8) ^ hm)) = pk;
  }
  for (int i = tid; i < 512; i += 256) attn_s[i] = ATT[b*512 + i];
  __syncthreads();

  {
    const int pg = tid & 31, hd = tid >> 5;
    const long long base = ((long long)b*64 + hd*8)*HW + (long long)y*256 + pg*8;
    f16x8 vv[8], gg[8];
    #pragma unroll
    for (int d = 0; d < 8; ++d)
      vv[d] = *(const f16x8*)(Vv + base + (long long)d*HW);
    #pragma unroll
    for (int c = 0; c < 8; ++c)
      gg[c] = *(const f16x8*)(GG + base + (long long)c*HW);
    float a[8][8];
    #pragma unroll
    for (int c = 0; c < 8; ++c)
      #pragma unroll
      for (int d = 0; d < 8; ++d) a[c][d] = attn_s[hd*64 + c*8 + d];
    #pragma unroll
    for (int j = 0; j < 8; ++j) {
      int p = pg*8 + j;
      int hp = ((p & 7) ^ ((p >> 3) & 7)) << 4;
      f16x8 st;
      #pragma unroll
      for (int c = 0; c < 8; ++c) {
        float av = 0.f;
        #pragma unroll
        for (int d = 0; d < 8; ++d) av += a[c][d] * (float)vv[d][j];
        st[c] = (f16)((float)gg[c][j] * av);
      }
      *(f16x8*)(xs + p*128 + ((hd*16) ^ hp)) = st;
    }
  }
  __syncthreads();

  const int wave = tid >> 6, lane = tid & 63;
  const int n0 = wave * 64;
  const int lr = lane & 15, lg = lane >> 4;

  f32x4 acc[4][4];
  #pragma unroll
  for (int i = 0; i < 4; ++i)
    #pragma unroll
    for (int j = 0; j < 4; ++j) acc[i][j] = (f32x4){0.f,0.f,0.f,0.f};

  #pragma unroll
  for (int ks = 0; ks < 2; ++ks) {
    f16x8 af[4], bfr[4];
    #pragma unroll
    for (int mi = 0; mi < 4; ++mi) {
      int m = mi*16 + lr;
      int hm = ((m & 7) ^ ((m >> 3) & 7)) << 4;
      af[mi] = *(const f16x8*)(wl + m*128 + ((ks*64 + lg*16) ^ hm));
    }
    #pragma unroll
    for (int ni = 0; ni < 4; ++ni) {
      int p = n0 + ni*16 + lr;
      int hp = ((p & 7) ^ ((p >> 3) & 7)) << 4;
      bfr[ni] = *(const f16x8*)(xs + p*128 + ((ks*64 + lg*16) ^ hp));
    }
    #pragma unroll
    for (int mi = 0; mi < 4; ++mi)
      #pragma unroll
      for (int ni = 0; ni < 4; ++ni)
        acc[mi][ni] = __builtin_amdgcn_mfma_f32_16x16x32_f16(
            af[mi], bfr[ni], acc[mi][ni], 0, 0, 0);
  }

  const long long obase = (long long)b*64*HW + (long long)y*256;
  #pragma unroll
  for (int mi = 0; mi < 4; ++mi)
    #pragma unroll
    for (int ni = 0; ni < 4; ++ni)
      #pragma unroll
      for (int r = 0; r < 4; ++r) {
        int m = mi*16 + lg*4 + r;
        int p = n0 + ni*16 + lr;
        out[obase + (long long)m*HW + p] = acc[mi][ni][r];
      }
}

// ---------------------------------------------------------------------------
extern "C" void kernel_launch(void* const* d_in, const int* in_sizes, int n_in,
                              void* d_out, int out_size, void* d_ws, size_t ws_size,
                              hipStream_t stream)
{
  float* out = (float*)d_out;

  int mp[7] = {-1,-1,-1,-1,-1,-1,-1};
  bool ok = (n_in == 7);
  if (ok) {
    int n4 = 0;
    for (int i = 0; i < 7; ++i) {
      long s = in_sizes[i];
      if      (s == 33554432) mp[0] = i;            // x
      else if (s == 576)      mp[2] = i;            // w_gate_dw
      else if (s == 12288)    mp[3] = i;            // w_qkv
      else if (s == 1728)     mp[4] = i;            // w_qkv_dw
      else if (s == 8)        mp[6] = i;            // temperature
      else if (s == 4096)     { if (n4 == 0) mp[1] = i; else mp[5] = i; ++n4; }
    }
    ok = ok && (n4 == 2);
    for (int i = 0; i < 7; ++i) ok = ok && (mp[i] >= 0);
  }
  if (!ok) { k_signal<<<2048,256,0,stream>>>(out, (long long)out_size, 2000.0f); return; }
  if (out_size != 33554432) { k_signal<<<2048,256,0,stream>>>(out, (long long)out_size, 3000.0f); return; }

  const float* x    = (const float*)d_in[mp[0]];
  const float* wg   = (const float*)d_in[mp[1]];
  const float* wgd  = (const float*)d_in[mp[2]];
  const float* wqkv = (const float*)d_in[mp[3]];
  const float* wqd  = (const float*)d_in[mp[4]];
  const float* wpj  = (const float*)d_in[mp[5]];
  const float* tp   = (const float*)d_in[mp[6]];

  unsigned char* ws = (unsigned char*)d_ws;
  const size_t GRP_SZ   = 8UL*8*NBAND*80*4;
  const size_t FULL     = 402653184UL + GRP_SZ + 16384UL + 32768UL;
  const size_t PERB_GRP = 8UL*NBAND*80*4;
  const size_t PERB     = 50331648UL + PERB_GRP + 2048UL + 32768UL;

  if (ws != nullptr && ws_size >= FULL) {
    f16*   A    = (f16*)ws;
    f16*   Vv   = (f16*)(ws + 268435456UL);
    f16*   GG   = (f16*)(ws + 335544320UL);
    float* GRP  = (float*)(ws + 402653184UL);
    float* ATT  = (float*)(ws + 402653184UL + GRP_SZ);
    f16*   W16  = (f16*)(ws + 402653184UL + GRP_SZ + 16384UL);
    k0_wconv<<<16,   256, 0, stream>>>(wg, wqkv, W16);
    k1_mfma <<<2048, 256, 0, stream>>>(x, W16, A);
    k2a_dw  <<<4096, 256, 0, stream>>>(A, wgd, wqd, Vv, GG);
    k2b_qk  <<<8*8*NBAND, 64, 0, stream>>>(A, wqd, GRP);
    k2c_attn<<<64,   64,  0, stream>>>(GRP, tp, ATT);
    k3_out  <<<2048, 256, 0, stream>>>(Vv, GG, ATT, wpj, out);
  } else if (ws != nullptr && ws_size >= PERB) {
    f16*   A    = (f16*)ws;
    f16*   Vv   = (f16*)(ws + 33554432UL);
    f16*   GG   = (f16*)(ws + 41943040UL);
    float* GRP  = (float*)(ws + 50331648UL);
    float* ATT  = (float*)(ws + 50331648UL + PERB_GRP);
    f16*   W16  = (f16*)(ws + 50331648UL + PERB_GRP + 2048UL);
    k0_wconv<<<16, 256, 0, stream>>>(wg, wqkv, W16);
    for (int b = 0; b < 8; ++b) {
      const float* xb = x + (long long)b*64*HW;
      float* ob = out + (long long)b*64*HW;
      k1_mfma <<<256,  256, 0, stream>>>(xb, W16, A);
      k2a_dw  <<<512,  256, 0, stream>>>(A, wgd, wqd, Vv, GG);
      k2b_qk  <<<8*NBAND, 64, 0, stream>>>(A, wqd, GRP);
      k2c_attn<<<8,    64,  0, stream>>>(GRP, tp, ATT);
      k3_out  <<<256,  256, 0, stream>>>(Vv, GG, ATT, wpj, ob);
    }
  } else {
    k_signal<<<2048,256,0,stream>>>(out, (long long)out_size, 1000.0f);
  }
}